// Round 12
// baseline (140.193 us; speedup 1.0000x reference)
//
#include <hip/hip_runtime.h>
#include <math.h>

#define PI9 (2.0f * 3.14159265358979323846f / 9.0f)

typedef float f32x4 __attribute__((ext_vector_type(4)));
typedef unsigned short us8 __attribute__((ext_vector_type(8)));
typedef __bf16 bf16x8 __attribute__((ext_vector_type(8)));
typedef unsigned int u32x4 __attribute__((ext_vector_type(4)));

__device__ __forceinline__ float ssp_f(float x) {
  const float ax = fabsf(x);
  const float t = __expf(-ax);
  return fmaxf(x, 0.f) + __logf(1.f + t) - 0.69314718f;
}

__device__ __forceinline__ unsigned short f2bf(float f) {
  unsigned int u = __float_as_uint(f);
  unsigned int r = (u + 0x7FFFu + ((u >> 16) & 1u)) >> 16;
  return (unsigned short)r;
}

// ===========================================================================
// precompute_C body (9 blocks, one d-slice each) -> CT[d][p][q pad 12]
// ===========================================================================
__device__ void precompute_body(
    int d, unsigned char* smem,
    const float* __restrict__ Ux_re, const float* __restrict__ Ux_im,
    const float* __restrict__ Uf_re, const float* __restrict__ Uf_im,
    const float* __restrict__ Vo_re, const float* __restrict__ Vo_im,
    float* __restrict__ CT) {
  float* G = (float*)smem;                // 2*729 f
  float* TL = (float*)(smem + 5840);      // 729 f
  float* cs9 = (float*)(smem + 8768);
  float* sn9 = (float*)(smem + 8816);
  const int t0 = threadIdx.x;

  if (t0 < 9) {
    float s, c;
    __sincosf(PI9 * (float)t0, &s, &c);
    cs9[t0] = c; sn9[t0] = s;
  }
  __syncthreads();

  for (int t = t0; t < 1458; t += 256) {
    const int which = t / 729, idx = t % 729;
    const int p = idx / 81, ab = idx % 81, a = ab / 9, b = ab % 9;
    const float* Ure = which ? Uf_re : Ux_re;
    const float* Uim = which ? Uf_im : Ux_im;
    float g = 0.f;
#pragma unroll
    for (int v = 0; v < 3; ++v) {
      const int uc = v + 2;
      float hre = 0.f, him = 0.f;
#pragma unroll
      for (int ui = 0; ui < 5; ++ui) {
        const int u = (ui + 7) % 9;
        const float re = Ure[p * 25 + ui * 5 + uc];
        const float im = Uim[p * 25 + ui * 5 + uc];
        const int k = (u * a) % 9;
        const float c = cs9[k], s = sn9[k];
        hre += re * c - im * s;
        him += re * s + im * c;
      }
      hre *= (1.f / 9.f); him *= (1.f / 9.f);
      if (v == 0) {
        g += hre;
      } else {
        const int k = (v * b) % 9;
        g += 2.f * (hre * cs9[k] - him * sn9[k]);
      }
    }
    G[which * 729 + p * 81 + ab] = g * (1.f / 9.f);
  }
  __syncthreads();

  for (int t = t0; t < 729; t += 256) {
    const int ab = t / 9, dd = t % 9, a = ab / 9, b = ab % 9;
    float acc = 0.f;
    for (int u = 0; u < 9; ++u)
      for (int v = 0; v < 5; ++v) {
        const int k = (u * a + v * b) % 9;
        acc += Vo_re[u * 45 + v * 9 + dd] * cs9[k]
             + Vo_im[u * 45 + v * 9 + dd] * sn9[k];
      }
    TL[ab * 9 + dd] = acc;
  }
  __syncthreads();

  if (t0 < 108) {
    const int p = t0 / 12, q = t0 % 12;
    float acc = 0.f;
    if (q < 9) {
      for (int ab = 0; ab < 81; ++ab)
        acc += G[p * 81 + ab] * G[729 + q * 81 + ab] * TL[ab * 9 + d];
    }
    CT[(d * 9 + p) * 12 + q] = acc;
  }
}

// ===========================================================================
// MLP body (4 reps = 256 edges / block); output w48b bf16 padded [e][16][4]
// ===========================================================================
__device__ void mlp_body(
    int mblk, unsigned char* smem, const float* __restrict__ win,
    const float* __restrict__ W1, const float* __restrict__ W2,
    const float* __restrict__ W3, const float* __restrict__ a_w,
    const float* __restrict__ den, unsigned short* __restrict__ w48b) {
  float* W1s = (float*)smem;                              // 2048 B
  unsigned short* W2T = (unsigned short*)(smem + 2048);   // 8192 B
  unsigned short* W3T = (unsigned short*)(smem + 10240);  // 6144 B
  unsigned short* H1 = (unsigned short*)(smem + 16384);   // 8192 B
  unsigned short* H2 = (unsigned short*)(smem + 24576);   // 8192 B
  const int t = threadIdx.x;

  const float invden = 1.f / den[0];
  const float sc0 = a_w[0] * invden, sc1 = a_w[10] * invden, sc2 = a_w[22] * invden;
  const float rs8 = 0.35355339059327373f;

  if (t < 128) {
    float4 v = ((const float4*)W1)[t];
    v.x *= rs8; v.y *= rs8; v.z *= rs8; v.w *= rs8;
    ((float4*)W1s)[t] = v;
  }
  for (int i = t; i < 4096; i += 256) {
    const int k = i >> 6, j = i & 63;
    W2T[j * 64 + ((((k >> 3) ^ (j & 7)) << 3)) + (k & 7)] = f2bf(W2[i] * 0.125f);
  }
  for (int i = t; i < 3072; i += 256) {
    const int k = i / 48, j = i % 48;
    const int jm = j % 3;
    const float s = (jm == 0) ? sc0 : ((jm == 1) ? sc1 : sc2);
    W3T[j * 64 + ((((k >> 3) ^ (j & 7)) << 3)) + (k & 7)] = f2bf(W3[i] * 0.125f * s);
  }
  __syncthreads();

  const int w = t >> 6, l = t & 63;
  const int er = l & 15, g = l >> 4;
  unsigned short* h1p = H1 + w * 1024;
  unsigned short* h2p = H2 + w * 1024;

#pragma unroll 1
  for (int rep = 0; rep < 4; ++rep) {
    const int e = mblk * 256 + rep * 64 + w * 16 + er;

    float in8[8];
    {
      const float4 A = *(const float4*)(win + (size_t)e * 8);
      const float4 B = *(const float4*)(win + (size_t)e * 8 + 4);
      in8[0] = A.x; in8[1] = A.y; in8[2] = A.z; in8[3] = A.w;
      in8[4] = B.x; in8[5] = B.y; in8[6] = B.z; in8[7] = B.w;
    }
    float h[16];
#pragma unroll
    for (int c = 0; c < 16; ++c) h[c] = 0.f;
#pragma unroll
    for (int k = 0; k < 8; ++k) {
      const float* wr = &W1s[k * 64 + g * 16];
      const float4 w0 = *(const float4*)wr;
      const float4 w1 = *(const float4*)(wr + 4);
      const float4 w2 = *(const float4*)(wr + 8);
      const float4 w3 = *(const float4*)(wr + 12);
      const float ik = in8[k];
      h[0]  = fmaf(ik, w0.x, h[0]);  h[1]  = fmaf(ik, w0.y, h[1]);
      h[2]  = fmaf(ik, w0.z, h[2]);  h[3]  = fmaf(ik, w0.w, h[3]);
      h[4]  = fmaf(ik, w1.x, h[4]);  h[5]  = fmaf(ik, w1.y, h[5]);
      h[6]  = fmaf(ik, w1.z, h[6]);  h[7]  = fmaf(ik, w1.w, h[7]);
      h[8]  = fmaf(ik, w2.x, h[8]);  h[9]  = fmaf(ik, w2.y, h[9]);
      h[10] = fmaf(ik, w2.z, h[10]); h[11] = fmaf(ik, w2.w, h[11]);
      h[12] = fmaf(ik, w3.x, h[12]); h[13] = fmaf(ik, w3.y, h[13]);
      h[14] = fmaf(ik, w3.z, h[14]); h[15] = fmaf(ik, w3.w, h[15]);
    }
    us8 pk0, pk1;
#pragma unroll
    for (int jj = 0; jj < 8; ++jj) pk0[jj] = f2bf(ssp_f(h[jj]));
#pragma unroll
    for (int jj = 0; jj < 8; ++jj) pk1[jj] = f2bf(ssp_f(h[8 + jj]));
    *(us8*)&h1p[er * 64 + (((2 * g) ^ (er & 7)) << 3)] = pk0;
    *(us8*)&h1p[er * 64 + (((2 * g + 1) ^ (er & 7)) << 3)] = pk1;
    __builtin_amdgcn_wave_barrier();

    const us8 a0 = *(const us8*)&h1p[er * 64 + ((g ^ (er & 7)) << 3)];
    const us8 a1 = *(const us8*)&h1p[er * 64 + (((g + 4) ^ (er & 7)) << 3)];
    float hh[16];
#pragma unroll
    for (int nt = 0; nt < 4; ++nt) {
      const int j = nt * 16 + er;
      const us8 b0 = *(const us8*)&W2T[j * 64 + ((g ^ (j & 7)) << 3)];
      const us8 b1 = *(const us8*)&W2T[j * 64 + (((g + 4) ^ (j & 7)) << 3)];
      f32x4 acc = {0.f, 0.f, 0.f, 0.f};
      acc = __builtin_amdgcn_mfma_f32_16x16x32_bf16(
          __builtin_bit_cast(bf16x8, a0), __builtin_bit_cast(bf16x8, b0), acc, 0, 0, 0);
      acc = __builtin_amdgcn_mfma_f32_16x16x32_bf16(
          __builtin_bit_cast(bf16x8, a1), __builtin_bit_cast(bf16x8, b1), acc, 0, 0, 0);
#pragma unroll
      for (int r = 0; r < 4; ++r) hh[nt * 4 + r] = ssp_f(acc[r]);
    }
#pragma unroll
    for (int nt = 0; nt < 4; ++nt)
#pragma unroll
      for (int r = 0; r < 4; ++r) {
        const int e2 = g * 4 + r;
        const int k2 = nt * 16 + er;
        h2p[e2 * 64 + ((((k2 >> 3) ^ (e2 & 7)) << 3)) + (k2 & 7)] = f2bf(hh[nt * 4 + r]);
      }
    __builtin_amdgcn_wave_barrier();

    const us8 c0 = *(const us8*)&h2p[er * 64 + ((g ^ (er & 7)) << 3)];
    const us8 c1 = *(const us8*)&h2p[er * 64 + (((g + 4) ^ (er & 7)) << 3)];
    const int ebase = mblk * 256 + rep * 64 + w * 16 + g * 4;
#pragma unroll
    for (int nt = 0; nt < 3; ++nt) {
      const int o = nt * 16 + er;
      const int om = o / 3, ol = o - om * 3;
      const us8 b0 = *(const us8*)&W3T[o * 64 + ((g ^ (o & 7)) << 3)];
      const us8 b1 = *(const us8*)&W3T[o * 64 + (((g + 4) ^ (o & 7)) << 3)];
      f32x4 acc = {0.f, 0.f, 0.f, 0.f};
      acc = __builtin_amdgcn_mfma_f32_16x16x32_bf16(
          __builtin_bit_cast(bf16x8, c0), __builtin_bit_cast(bf16x8, b0), acc, 0, 0, 0);
      acc = __builtin_amdgcn_mfma_f32_16x16x32_bf16(
          __builtin_bit_cast(bf16x8, c1), __builtin_bit_cast(bf16x8, b1), acc, 0, 0, 0);
#pragma unroll
      for (int r = 0; r < 4; ++r)
        w48b[(size_t)(ebase + r) * 64 + om * 4 + ol] = f2bf(acc[r]);
    }
    __builtin_amdgcn_wave_barrier();
  }
}

// ===========================================================================
// prep: [0,nMlp) MLP | [+nScat) scatter (packed int2 {e,src}) | [+9) CT
// ===========================================================================
__global__ __launch_bounds__(256) void prep_kernel(
    const float* __restrict__ win, const float* __restrict__ W1,
    const float* __restrict__ W2, const float* __restrict__ W3,
    const float* __restrict__ a_w, const float* __restrict__ den,
    unsigned short* __restrict__ w48b,
    const int* __restrict__ dst, const int* __restrict__ src, int E,
    int* __restrict__ cnt, int2* __restrict__ slots2,
    const float* __restrict__ Ux_re, const float* __restrict__ Ux_im,
    const float* __restrict__ Uf_re, const float* __restrict__ Uf_im,
    const float* __restrict__ Vo_re, const float* __restrict__ Vo_im,
    float* __restrict__ CT, int nMlp, int nScat) {
  __shared__ __align__(16) unsigned char smem[32768];
  const int bid = blockIdx.x;
  if (bid < nMlp) {
    mlp_body(bid, smem, win, W1, W2, W3, a_w, den, w48b);
  } else if (bid < nMlp + nScat) {
    const int e = (bid - nMlp) * 256 + threadIdx.x;
    if (e < E) {
      const int d = dst[e];
      const int pos = atomicAdd(&cnt[d], 1);
      if (pos < 96) slots2[(size_t)d * 96 + pos] = make_int2(e, src[e]);
    }
  } else {
    precompute_body(bid - nMlp - nScat, smem, Ux_re, Ux_im, Uf_re, Uf_im,
                    Vo_re, Vo_im, CT);
  }
}

// ===========================================================================
// Node kernel v11: BLOCK-per-node, 4 waves share one 16-edge batch.
//  - Me: 6 MFMAs split across waves (w0:{0,1} w1:{2,3} w2:{4} w3:{5}),
//    shared meL[16 edges][9 d][16 shorts] = 4.6 KB
//  - message: 4 edges/wave, fully unrolled (4-deep VMEM), acc in C-regs
//  - final 4-way cross-wave f32x4 reduce (3 KB)
// ===========================================================================
__global__ __launch_bounds__(256) void node_kernel(
    const float* __restrict__ x, const float* __restrict__ filt,
    const int* __restrict__ cnt, const int2* __restrict__ slots2,
    const unsigned short* __restrict__ w48b, const float* __restrict__ CT,
    float* __restrict__ out, int N) {
  __shared__ __align__(16) unsigned short meL[16 * 9 * 16];  // il*144 + d*16 + p
  __shared__ __align__(16) float part[3][64][4];
  const int t = threadIdx.x, w = t >> 6, l = t & 63;
  const int n16 = l & 15, g = l >> 4;
  const int Ld = (n16 == 0) ? 0 : ((n16 < 4) ? 1 : 2);
  const bool dok = n16 < 9;
  const int drow = dok ? n16 : 0;
  const int n = blockIdx.x;

  // per-wave Me tile assignment
  const int tA = (w == 0) ? 0 : (w == 1) ? 2 : (w == 2) ? 4 : 5;
  const int tB = (w == 0) ? 1 : (w == 1) ? 3 : -1;

  int dA, pA; bool okA;
  bf16x8 BmeA;
  {
    const int col = tA * 16 + n16;
    okA = (col < 81);
    dA = okA ? col / 9 : 0;
    pA = okA ? col % 9 : 0;
    bf16x8 bv;
#pragma unroll
    for (int j = 0; j < 8; ++j) bv[j] = (__bf16)0.f;
    if (okA) {
      const float* cp = CT + col * 12;
      if (g == 0) {
        const float4 ca = *(const float4*)cp;
        const float4 cb = *(const float4*)(cp + 4);
        bv[0] = (__bf16)ca.x; bv[1] = (__bf16)ca.y;
        bv[2] = (__bf16)ca.z; bv[3] = (__bf16)ca.w;
        bv[4] = (__bf16)cb.x; bv[5] = (__bf16)cb.y;
        bv[6] = (__bf16)cb.z; bv[7] = (__bf16)cb.w;
      } else if (g == 1) {
        bv[0] = (__bf16)cp[8];
      }
    }
    BmeA = bv;
  }
  int dB = 0, pB = 0; bool okB = false;
  bf16x8 BmeB;
#pragma unroll
  for (int j = 0; j < 8; ++j) BmeB[j] = (__bf16)0.f;
  if (tB >= 0) {
    const int col = tB * 16 + n16;
    okB = (col < 81);
    dB = okB ? col / 9 : 0;
    pB = okB ? col % 9 : 0;
    if (okB) {
      const float* cp = CT + col * 12;
      if (g == 0) {
        const float4 ca = *(const float4*)cp;
        const float4 cb = *(const float4*)(cp + 4);
        BmeB[0] = (__bf16)ca.x; BmeB[1] = (__bf16)ca.y;
        BmeB[2] = (__bf16)ca.z; BmeB[3] = (__bf16)ca.w;
        BmeB[4] = (__bf16)cb.x; BmeB[5] = (__bf16)cb.y;
        BmeB[6] = (__bf16)cb.z; BmeB[7] = (__bf16)cb.w;
      } else if (g == 1) {
        BmeB[0] = (__bf16)cp[8];
      }
    }
  }

  int deg = cnt[n];
  if (deg > 96) deg = 96;
  const int2* sl2 = slots2 + (size_t)n * 96;

  f32x4 accm = {0.f, 0.f, 0.f, 0.f};

  const int nb = (deg + 15) >> 4;
  for (int b = 0; b < nb; ++b) {
    const int base = b * 16;
    const int degb = (deg - base < 16) ? (deg - base) : 16;

    // batch edge list into lanes (lane n16 holds edge n16)
    int esx = 0, esy = 0;
    if (n16 < degb) {
      const int2 v = sl2[base + n16];
      esx = v.x; esy = v.y;
    }
    // Me A-frag: f rows (k = q)
    bf16x8 Af;
#pragma unroll
    for (int j = 0; j < 8; ++j) Af[j] = (__bf16)0.f;
    if (n16 < degb) {
      const float* fp = filt + (size_t)esx * 9;
      if (g == 0) {
        const float4 fa = *(const float4*)fp;
        const float4 fb = *(const float4*)(fp + 4);
        Af[0] = (__bf16)fa.x; Af[1] = (__bf16)fa.y;
        Af[2] = (__bf16)fa.z; Af[3] = (__bf16)fa.w;
        Af[4] = (__bf16)fb.x; Af[5] = (__bf16)fb.y;
        Af[6] = (__bf16)fb.z; Af[7] = (__bf16)fb.w;
      } else if (g == 1) {
        Af[0] = (__bf16)fp[8];
      }
    }

    if (b) __syncthreads();   // prev message phase done before overwrite

    // this wave's Me MFMAs -> shared meL  (row er = g*4+r, col (d,p))
    {
      f32x4 a6 = {0.f, 0.f, 0.f, 0.f};
      a6 = __builtin_amdgcn_mfma_f32_16x16x32_bf16(Af, BmeA, a6, 0, 0, 0);
      if (okA) {
#pragma unroll
        for (int r = 0; r < 4; ++r)
          meL[(g * 4 + r) * 144 + dA * 16 + pA] = f2bf(a6[r]);
      }
    }
    if (tB >= 0) {
      f32x4 a6 = {0.f, 0.f, 0.f, 0.f};
      a6 = __builtin_amdgcn_mfma_f32_16x16x32_bf16(Af, BmeB, a6, 0, 0, 0);
      if (okB) {
#pragma unroll
        for (int r = 0; r < 4; ++r)
          meL[(g * 4 + r) * 144 + dB * 16 + pB] = f2bf(a6[r]);
      }
    }
    __syncthreads();

    // ---- message phase: this wave's 4 edges, loads first (4-deep)
    float4 xa_[4], xb_[4];
    float x8_[4];
    float w0_[4], w1_[4], w2_[4];
    int il_[4];
#pragma unroll
    for (int j = 0; j < 4; ++j) {
      const int il = w * 4 + j;
      il_[j] = il;
      const int e = __builtin_amdgcn_readlane(esx, il);
      const int s = __builtin_amdgcn_readlane(esy, il);
      const bool act = il < degb;
      const float* xr = x + (size_t)s * 144 + n16 * 9;
      xa_[j] = *(const float4*)xr;
      xb_[j] = *(const float4*)(xr + 4);
      x8_[j] = xr[8];
      const uint2 wv = *(const uint2*)(w48b + (size_t)e * 64 + n16 * 4);
      w0_[j] = act ? __uint_as_float(wv.x << 16) : 0.f;
      w1_[j] = act ? __uint_as_float(wv.x & 0xffff0000u) : 0.f;
      w2_[j] = act ? __uint_as_float(wv.y << 16) : 0.f;
    }
#pragma unroll
    for (int j = 0; j < 4; ++j) {
      const float4 xa = xa_[j], xb = xb_[j];
      const float x8v = x8_[j];
      const float w0 = w0_[j], w1 = w1_[j], w2 = w2_[j];
      const unsigned short* mr = meL + il_[j] * 144 + drow * 16;
      const u32x4 mdv = *(const u32x4*)mr;
      const unsigned int md0 = mdv[0], md1 = mdv[1], md2 = mdv[2], md3 = mdv[3];
      const unsigned int md4 = *(const unsigned int*)(mr + 8);

      bf16x8 A;
      unsigned int B0, B1, B2, B3;
      if (g == 0) {
        A[0] = (__bf16)(xa.x * w0); A[1] = (__bf16)(xa.y * w0);
        A[2] = (__bf16)(xa.z * w0); A[3] = (__bf16)(xa.w * w0);
        A[4] = (__bf16)(xb.x * w0); A[5] = (__bf16)(xb.y * w0);
        A[6] = (__bf16)(xb.z * w0); A[7] = (__bf16)(xb.w * w0);
        const bool s0 = (Ld == 0);
        B0 = s0 ? md0 : 0u; B1 = s0 ? md1 : 0u;
        B2 = s0 ? md2 : 0u; B3 = s0 ? md3 : 0u;
      } else if (g == 1) {
        A[0] = (__bf16)(x8v * w0);  A[1] = (__bf16)(xa.x * w1);
        A[2] = (__bf16)(xa.y * w1); A[3] = (__bf16)(xa.z * w1);
        A[4] = (__bf16)(xa.w * w1); A[5] = (__bf16)(xb.x * w1);
        A[6] = (__bf16)(xb.y * w1); A[7] = (__bf16)(xb.z * w1);
        const bool s0 = (Ld == 0), s1 = (Ld == 1);
        B0 = (s0 ? (md4 & 0xffffu) : 0u) | (s1 ? (md0 << 16) : 0u);
        B1 = s1 ? ((md0 >> 16) | (md1 << 16)) : 0u;
        B2 = s1 ? ((md1 >> 16) | (md2 << 16)) : 0u;
        B3 = s1 ? ((md2 >> 16) | (md3 << 16)) : 0u;
      } else if (g == 2) {
        A[0] = (__bf16)(xb.w * w1); A[1] = (__bf16)(x8v * w1);
        A[2] = (__bf16)(xa.x * w2); A[3] = (__bf16)(xa.y * w2);
        A[4] = (__bf16)(xa.z * w2); A[5] = (__bf16)(xa.w * w2);
        A[6] = (__bf16)(xb.x * w2); A[7] = (__bf16)(xb.y * w2);
        const bool s1 = (Ld == 1), s2 = (Ld == 2);
        B0 = s1 ? ((md3 >> 16) | (md4 << 16)) : 0u;
        B1 = s2 ? md0 : 0u; B2 = s2 ? md1 : 0u; B3 = s2 ? md2 : 0u;
      } else {
        A[0] = (__bf16)(xb.z * w2); A[1] = (__bf16)(xb.w * w2);
        A[2] = (__bf16)(x8v * w2);
        A[3] = (__bf16)0.f; A[4] = (__bf16)0.f; A[5] = (__bf16)0.f;
        A[6] = (__bf16)0.f; A[7] = (__bf16)0.f;
        const bool s2 = (Ld == 2);
        B0 = s2 ? md3 : 0u;
        B1 = s2 ? (md4 & 0xffffu) : 0u;
        B2 = 0u; B3 = 0u;
      }
      u32x4 bv = {B0, B1, B2, B3};
      accm = __builtin_amdgcn_mfma_f32_16x16x32_bf16(
          A, __builtin_bit_cast(bf16x8, bv), accm, 0, 0, 0);
    }
  }

  // ---- cross-wave reduce + write (C layout: col d = lane&15, row m = g*4+r)
  if (w > 0) {
#pragma unroll
    for (int r = 0; r < 4; ++r) part[w - 1][l][r] = accm[r];
  }
  __syncthreads();
  if (w == 0 && dok) {
    float* op = out + (size_t)n * 144 + (g * 4) * 9 + n16;
    op[0]  = accm[0] + part[0][l][0] + part[1][l][0] + part[2][l][0];
    op[9]  = accm[1] + part[0][l][1] + part[1][l][1] + part[2][l][1];
    op[18] = accm[2] + part[0][l][2] + part[1][l][2] + part[2][l][2];
    op[27] = accm[3] + part[0][l][3] + part[1][l][3] + part[2][l][3];
  }
}

// ---------------------------------------------------------------------------
extern "C" void kernel_launch(void* const* d_in, const int* in_sizes, int n_in,
                              void* d_out, int out_size, void* d_ws, size_t ws_size,
                              hipStream_t stream) {
  const float* x      = (const float*)d_in[0];
  const float* filt   = (const float*)d_in[1];
  const float* win    = (const float*)d_in[2];
  const int*   eidx   = (const int*)d_in[3];
  const float* Ux_re  = (const float*)d_in[4];
  const float* Ux_im  = (const float*)d_in[5];
  const float* Uf_re  = (const float*)d_in[6];
  const float* Uf_im  = (const float*)d_in[7];
  const float* Vo_re  = (const float*)d_in[8];
  const float* Vo_im  = (const float*)d_in[9];
  const float* W1     = (const float*)d_in[10];
  const float* W2     = (const float*)d_in[11];
  const float* W3     = (const float*)d_in[12];
  const float* a_w    = (const float*)d_in[13];
  const float* den    = (const float*)d_in[14];
  float* out = (float*)d_out;

  const int N = in_sizes[0] / 144;          // 10000
  const int E = in_sizes[3] / 2;            // 160000
  const int* dst = eidx;
  const int* src = eidx + E;

  char* wsb = (char*)d_ws;
  const size_t off_cnt  = 8192;
  const size_t off_slot = off_cnt + 40960;
  const size_t off_w48  = off_slot + (size_t)N * 96 * 8;

  float*          CT    = (float*)wsb;
  int*            cnt   = (int*)(wsb + off_cnt);
  int2*           slot2 = (int2*)(wsb + off_slot);
  unsigned short* w48b  = (unsigned short*)(wsb + off_w48);  // E*64 shorts

  const int nMlp  = E / 256;                // 625
  const int nScat = (E + 255) / 256;        // 625

  hipMemsetAsync(cnt, 0, (size_t)N * sizeof(int), stream);
  prep_kernel<<<nMlp + nScat + 9, 256, 0, stream>>>(
      win, W1, W2, W3, a_w, den, w48b,
      dst, src, E, cnt, slot2,
      Ux_re, Ux_im, Uf_re, Uf_im, Vo_re, Vo_im, CT, nMlp, nScat);
  node_kernel<<<N, 256, 0, stream>>>(
      x, filt, cnt, slot2, w48b, CT, out, N);
}

// Round 13
// 108.111 us; speedup vs baseline: 1.2968x; 1.2968x over previous
//
#include <hip/hip_runtime.h>
#include <math.h>

#define PI9 (2.0f * 3.14159265358979323846f / 9.0f)

typedef float f32x4 __attribute__((ext_vector_type(4)));
typedef unsigned short us8 __attribute__((ext_vector_type(8)));
typedef __bf16 bf16x8 __attribute__((ext_vector_type(8)));
typedef unsigned int u32x4 __attribute__((ext_vector_type(4)));

__device__ __forceinline__ float ssp_f(float x) {
  const float ax = fabsf(x);
  const float t = __expf(-ax);
  return fmaxf(x, 0.f) + __logf(1.f + t) - 0.69314718f;
}

__device__ __forceinline__ unsigned short f2bf(float f) {
  unsigned int u = __float_as_uint(f);
  unsigned int r = (u + 0x7FFFu + ((u >> 16) & 1u)) >> 16;
  return (unsigned short)r;
}

__device__ __forceinline__ float bfLO(unsigned int u) {
  return __uint_as_float(u << 16);
}
__device__ __forceinline__ float bfHI(unsigned int u) {
  return __uint_as_float(u & 0xffff0000u);
}

// ===========================================================================
// precompute_C body (9 blocks, one d-slice each) -> CT[d][p][q pad 12]
// ===========================================================================
__device__ void precompute_body(
    int d, unsigned char* smem,
    const float* __restrict__ Ux_re, const float* __restrict__ Ux_im,
    const float* __restrict__ Uf_re, const float* __restrict__ Uf_im,
    const float* __restrict__ Vo_re, const float* __restrict__ Vo_im,
    float* __restrict__ CT) {
  float* G = (float*)smem;                // 2*729 f
  float* TL = (float*)(smem + 5840);      // 729 f
  float* cs9 = (float*)(smem + 8768);
  float* sn9 = (float*)(smem + 8816);
  const int t0 = threadIdx.x;

  if (t0 < 9) {
    float s, c;
    __sincosf(PI9 * (float)t0, &s, &c);
    cs9[t0] = c; sn9[t0] = s;
  }
  __syncthreads();

  for (int t = t0; t < 1458; t += 256) {
    const int which = t / 729, idx = t % 729;
    const int p = idx / 81, ab = idx % 81, a = ab / 9, b = ab % 9;
    const float* Ure = which ? Uf_re : Ux_re;
    const float* Uim = which ? Uf_im : Ux_im;
    float g = 0.f;
#pragma unroll
    for (int v = 0; v < 3; ++v) {
      const int uc = v + 2;
      float hre = 0.f, him = 0.f;
#pragma unroll
      for (int ui = 0; ui < 5; ++ui) {
        const int u = (ui + 7) % 9;
        const float re = Ure[p * 25 + ui * 5 + uc];
        const float im = Uim[p * 25 + ui * 5 + uc];
        const int k = (u * a) % 9;
        const float c = cs9[k], s = sn9[k];
        hre += re * c - im * s;
        him += re * s + im * c;
      }
      hre *= (1.f / 9.f); him *= (1.f / 9.f);
      if (v == 0) {
        g += hre;
      } else {
        const int k = (v * b) % 9;
        g += 2.f * (hre * cs9[k] - him * sn9[k]);
      }
    }
    G[which * 729 + p * 81 + ab] = g * (1.f / 9.f);
  }
  __syncthreads();

  for (int t = t0; t < 729; t += 256) {
    const int ab = t / 9, dd = t % 9, a = ab / 9, b = ab % 9;
    float acc = 0.f;
    for (int u = 0; u < 9; ++u)
      for (int v = 0; v < 5; ++v) {
        const int k = (u * a + v * b) % 9;
        acc += Vo_re[u * 45 + v * 9 + dd] * cs9[k]
             + Vo_im[u * 45 + v * 9 + dd] * sn9[k];
      }
    TL[ab * 9 + dd] = acc;
  }
  __syncthreads();

  if (t0 < 108) {
    const int p = t0 / 12, q = t0 % 12;
    float acc = 0.f;
    if (q < 9) {
      for (int ab = 0; ab < 81; ++ab)
        acc += G[p * 81 + ab] * G[729 + q * 81 + ab] * TL[ab * 9 + d];
    }
    CT[(d * 9 + p) * 12 + q] = acc;
  }
}

// ===========================================================================
// MLP body (4 reps = 256 edges / block); output w48b bf16 padded [e][16][4]
// ===========================================================================
__device__ void mlp_body(
    int mblk, unsigned char* smem, const float* __restrict__ win,
    const float* __restrict__ W1, const float* __restrict__ W2,
    const float* __restrict__ W3, const float* __restrict__ a_w,
    const float* __restrict__ den, unsigned short* __restrict__ w48b) {
  float* W1s = (float*)smem;                              // 2048 B
  unsigned short* W2T = (unsigned short*)(smem + 2048);   // 8192 B
  unsigned short* W3T = (unsigned short*)(smem + 10240);  // 6144 B
  unsigned short* H1 = (unsigned short*)(smem + 16384);   // 8192 B
  unsigned short* H2 = (unsigned short*)(smem + 24576);   // 8192 B
  const int t = threadIdx.x;

  const float invden = 1.f / den[0];
  const float sc0 = a_w[0] * invden, sc1 = a_w[10] * invden, sc2 = a_w[22] * invden;
  const float rs8 = 0.35355339059327373f;

  if (t < 128) {
    float4 v = ((const float4*)W1)[t];
    v.x *= rs8; v.y *= rs8; v.z *= rs8; v.w *= rs8;
    ((float4*)W1s)[t] = v;
  }
  for (int i = t; i < 4096; i += 256) {
    const int k = i >> 6, j = i & 63;
    W2T[j * 64 + ((((k >> 3) ^ (j & 7)) << 3)) + (k & 7)] = f2bf(W2[i] * 0.125f);
  }
  for (int i = t; i < 3072; i += 256) {
    const int k = i / 48, j = i % 48;
    const int jm = j % 3;
    const float s = (jm == 0) ? sc0 : ((jm == 1) ? sc1 : sc2);
    W3T[j * 64 + ((((k >> 3) ^ (j & 7)) << 3)) + (k & 7)] = f2bf(W3[i] * 0.125f * s);
  }
  __syncthreads();

  const int w = t >> 6, l = t & 63;
  const int er = l & 15, g = l >> 4;
  unsigned short* h1p = H1 + w * 1024;
  unsigned short* h2p = H2 + w * 1024;

#pragma unroll 1
  for (int rep = 0; rep < 4; ++rep) {
    const int e = mblk * 256 + rep * 64 + w * 16 + er;

    float in8[8];
    {
      const float4 A = *(const float4*)(win + (size_t)e * 8);
      const float4 B = *(const float4*)(win + (size_t)e * 8 + 4);
      in8[0] = A.x; in8[1] = A.y; in8[2] = A.z; in8[3] = A.w;
      in8[4] = B.x; in8[5] = B.y; in8[6] = B.z; in8[7] = B.w;
    }
    float h[16];
#pragma unroll
    for (int c = 0; c < 16; ++c) h[c] = 0.f;
#pragma unroll
    for (int k = 0; k < 8; ++k) {
      const float* wr = &W1s[k * 64 + g * 16];
      const float4 w0 = *(const float4*)wr;
      const float4 w1 = *(const float4*)(wr + 4);
      const float4 w2 = *(const float4*)(wr + 8);
      const float4 w3 = *(const float4*)(wr + 12);
      const float ik = in8[k];
      h[0]  = fmaf(ik, w0.x, h[0]);  h[1]  = fmaf(ik, w0.y, h[1]);
      h[2]  = fmaf(ik, w0.z, h[2]);  h[3]  = fmaf(ik, w0.w, h[3]);
      h[4]  = fmaf(ik, w1.x, h[4]);  h[5]  = fmaf(ik, w1.y, h[5]);
      h[6]  = fmaf(ik, w1.z, h[6]);  h[7]  = fmaf(ik, w1.w, h[7]);
      h[8]  = fmaf(ik, w2.x, h[8]);  h[9]  = fmaf(ik, w2.y, h[9]);
      h[10] = fmaf(ik, w2.z, h[10]); h[11] = fmaf(ik, w2.w, h[11]);
      h[12] = fmaf(ik, w3.x, h[12]); h[13] = fmaf(ik, w3.y, h[13]);
      h[14] = fmaf(ik, w3.z, h[14]); h[15] = fmaf(ik, w3.w, h[15]);
    }
    us8 pk0, pk1;
#pragma unroll
    for (int jj = 0; jj < 8; ++jj) pk0[jj] = f2bf(ssp_f(h[jj]));
#pragma unroll
    for (int jj = 0; jj < 8; ++jj) pk1[jj] = f2bf(ssp_f(h[8 + jj]));
    *(us8*)&h1p[er * 64 + (((2 * g) ^ (er & 7)) << 3)] = pk0;
    *(us8*)&h1p[er * 64 + (((2 * g + 1) ^ (er & 7)) << 3)] = pk1;
    __builtin_amdgcn_wave_barrier();

    const us8 a0 = *(const us8*)&h1p[er * 64 + ((g ^ (er & 7)) << 3)];
    const us8 a1 = *(const us8*)&h1p[er * 64 + (((g + 4) ^ (er & 7)) << 3)];
    float hh[16];
#pragma unroll
    for (int nt = 0; nt < 4; ++nt) {
      const int j = nt * 16 + er;
      const us8 b0 = *(const us8*)&W2T[j * 64 + ((g ^ (j & 7)) << 3)];
      const us8 b1 = *(const us8*)&W2T[j * 64 + (((g + 4) ^ (j & 7)) << 3)];
      f32x4 acc = {0.f, 0.f, 0.f, 0.f};
      acc = __builtin_amdgcn_mfma_f32_16x16x32_bf16(
          __builtin_bit_cast(bf16x8, a0), __builtin_bit_cast(bf16x8, b0), acc, 0, 0, 0);
      acc = __builtin_amdgcn_mfma_f32_16x16x32_bf16(
          __builtin_bit_cast(bf16x8, a1), __builtin_bit_cast(bf16x8, b1), acc, 0, 0, 0);
#pragma unroll
      for (int r = 0; r < 4; ++r) hh[nt * 4 + r] = ssp_f(acc[r]);
    }
#pragma unroll
    for (int nt = 0; nt < 4; ++nt)
#pragma unroll
      for (int r = 0; r < 4; ++r) {
        const int e2 = g * 4 + r;
        const int k2 = nt * 16 + er;
        h2p[e2 * 64 + ((((k2 >> 3) ^ (e2 & 7)) << 3)) + (k2 & 7)] = f2bf(hh[nt * 4 + r]);
      }
    __builtin_amdgcn_wave_barrier();

    const us8 c0 = *(const us8*)&h2p[er * 64 + ((g ^ (er & 7)) << 3)];
    const us8 c1 = *(const us8*)&h2p[er * 64 + (((g + 4) ^ (er & 7)) << 3)];
    const int ebase = mblk * 256 + rep * 64 + w * 16 + g * 4;
#pragma unroll
    for (int nt = 0; nt < 3; ++nt) {
      const int o = nt * 16 + er;
      const int om = o / 3, ol = o - om * 3;
      const us8 b0 = *(const us8*)&W3T[o * 64 + ((g ^ (o & 7)) << 3)];
      const us8 b1 = *(const us8*)&W3T[o * 64 + (((g + 4) ^ (o & 7)) << 3)];
      f32x4 acc = {0.f, 0.f, 0.f, 0.f};
      acc = __builtin_amdgcn_mfma_f32_16x16x32_bf16(
          __builtin_bit_cast(bf16x8, c0), __builtin_bit_cast(bf16x8, b0), acc, 0, 0, 0);
      acc = __builtin_amdgcn_mfma_f32_16x16x32_bf16(
          __builtin_bit_cast(bf16x8, c1), __builtin_bit_cast(bf16x8, b1), acc, 0, 0, 0);
#pragma unroll
      for (int r = 0; r < 4; ++r)
        w48b[(size_t)(ebase + r) * 64 + om * 4 + ol] = f2bf(acc[r]);
    }
    __builtin_amdgcn_wave_barrier();
  }
}

// ===========================================================================
// prep: [0,nMlp) MLP | [+nScat) scatter | [+nXc) x->bf16 pad12 | [+9) CT
// ===========================================================================
__global__ __launch_bounds__(256) void prep_kernel(
    const float* __restrict__ win, const float* __restrict__ W1,
    const float* __restrict__ W2, const float* __restrict__ W3,
    const float* __restrict__ a_w, const float* __restrict__ den,
    unsigned short* __restrict__ w48b,
    const int* __restrict__ dst, const int* __restrict__ src, int E,
    int* __restrict__ cnt, int2* __restrict__ slots2,
    const float* __restrict__ xsrc, int NR, unsigned short* __restrict__ xbf,
    const float* __restrict__ Ux_re, const float* __restrict__ Ux_im,
    const float* __restrict__ Uf_re, const float* __restrict__ Uf_im,
    const float* __restrict__ Vo_re, const float* __restrict__ Vo_im,
    float* __restrict__ CT, int nMlp, int nScat, int nXc) {
  __shared__ __align__(16) unsigned char smem[32768];
  const int bid = blockIdx.x;
  if (bid < nMlp) {
    mlp_body(bid, smem, win, W1, W2, W3, a_w, den, w48b);
  } else if (bid < nMlp + nScat) {
    const int e = (bid - nMlp) * 256 + threadIdx.x;
    if (e < E) {
      const int d = dst[e];
      const int pos = atomicAdd(&cnt[d], 1);
      if (pos < 96) slots2[(size_t)d * 96 + pos] = make_int2(e, src[e]);
    }
  } else if (bid < nMlp + nScat + nXc) {
    // row r = (node, m); read 9 f32, write 12 bf16 (padded, aligned)
    const int r = (bid - nMlp - nScat) * 256 + threadIdx.x;
    if (r < NR) {
      const float* xp = xsrc + (size_t)r * 9;
      unsigned int u0 = (unsigned)f2bf(xp[0]) | ((unsigned)f2bf(xp[1]) << 16);
      unsigned int u1 = (unsigned)f2bf(xp[2]) | ((unsigned)f2bf(xp[3]) << 16);
      unsigned int u2 = (unsigned)f2bf(xp[4]) | ((unsigned)f2bf(xp[5]) << 16);
      unsigned int u3 = (unsigned)f2bf(xp[6]) | ((unsigned)f2bf(xp[7]) << 16);
      unsigned int u4 = (unsigned)f2bf(xp[8]);
      unsigned short* op = xbf + (size_t)r * 12;
      *(uint2*)op = make_uint2(u0, u1);
      *(uint2*)(op + 4) = make_uint2(u2, u3);
      *(uint2*)(op + 8) = make_uint2(u4, 0u);
    }
  } else {
    precompute_body(bid - nMlp - nScat - nXc, smem, Ux_re, Ux_im, Uf_re,
                    Uf_im, Vo_re, Vo_im, CT);
  }
}

// ===========================================================================
// Node kernel v12 = R11 structure (wave-per-node, private 16-edge batch,
// fused Me via 6 MFMAs, message MFMA per edge) with:
//  - meL stride 24 -> 16 shorts  (LDS 27.6 KB -> 18.4 KB, occupancy x1.6)
//  - x from bf16 L2-resident xbf (padded rows, aligned uint2 loads)
// ===========================================================================
__global__ __launch_bounds__(256) void node_kernel(
    const unsigned short* __restrict__ xbf, const float* __restrict__ filt,
    const int* __restrict__ cnt, const int2* __restrict__ slots2,
    const unsigned short* __restrict__ w48b, const float* __restrict__ CT,
    float* __restrict__ out, int N) {
  __shared__ __align__(16) unsigned short meL[4][2304];  // il*144 + d*16 + p
  const int t = threadIdx.x, w = t >> 6, l = t & 63;
  const int n16 = l & 15, g = l >> 4;
  const int Ld = (n16 == 0) ? 0 : ((n16 < 4) ? 1 : 2);
  const bool dok = n16 < 9;
  const int drow = dok ? n16 : 0;
  const int n = blockIdx.x * 4 + w;
  if (n >= N) return;

  // ---- per-lane constant: Me-MFMA B-frags (6 tiles) + (d,p) of my col/tile
  int dT0, pT0, dT1, pT1, dT2, pT2, dT3, pT3, dT4, pT4, dT5, pT5;
  bool ok0, ok1, ok2, ok3, ok4, ok5;
  bf16x8 Bme0, Bme1, Bme2, Bme3, Bme4, Bme5;
#define MKB(tt, Bv, dv, pv, okv)                                             \
  {                                                                          \
    const int col = tt * 16 + n16;                                           \
    okv = (col < 81);                                                        \
    dv = okv ? col / 9 : 0;                                                  \
    pv = okv ? col % 9 : 0;                                                  \
    bf16x8 bv;                                                               \
    _Pragma("unroll")                                                        \
    for (int j = 0; j < 8; ++j) bv[j] = (__bf16)0.f;                         \
    if (okv) {                                                               \
      const float* cp = CT + col * 12;                                       \
      if (g == 0) {                                                          \
        const float4 ca = *(const float4*)cp;                                \
        const float4 cb = *(const float4*)(cp + 4);                          \
        bv[0] = (__bf16)ca.x; bv[1] = (__bf16)ca.y;                          \
        bv[2] = (__bf16)ca.z; bv[3] = (__bf16)ca.w;                          \
        bv[4] = (__bf16)cb.x; bv[5] = (__bf16)cb.y;                          \
        bv[6] = (__bf16)cb.z; bv[7] = (__bf16)cb.w;                          \
      } else if (g == 1) {                                                   \
        bv[0] = (__bf16)cp[8];                                               \
      }                                                                      \
    }                                                                        \
    Bv = bv;                                                                 \
  }
  MKB(0, Bme0, dT0, pT0, ok0); MKB(1, Bme1, dT1, pT1, ok1);
  MKB(2, Bme2, dT2, pT2, ok2); MKB(3, Bme3, dT3, pT3, ok3);
  MKB(4, Bme4, dT4, pT4, ok4); MKB(5, Bme5, dT5, pT5, ok5);
#undef MKB

  int deg = cnt[n];
  if (deg > 96) deg = 96;
  const int2* sl2 = slots2 + (size_t)n * 96;
  unsigned short* mlw = &meL[w][0];

  f32x4 accm = {0.f, 0.f, 0.f, 0.f};

  const int nb = (deg + 15) >> 4;
  for (int b = 0; b < nb; ++b) {
    const int base = b * 16;
    const int degb = (deg - base < 16) ? (deg - base) : 16;

    // ---- batch edge list into lanes (er holds edge er) + Me A-frag
    int esx = 0, esy = 0;
    if (n16 < degb) {
      const int2 v = sl2[base + n16];
      esx = v.x; esy = v.y;
    }
    bf16x8 Af;
#pragma unroll
    for (int j = 0; j < 8; ++j) Af[j] = (__bf16)0.f;
    if (n16 < degb) {
      const float* fp = filt + (size_t)esx * 9;
      if (g == 0) {
        const float4 fa = *(const float4*)fp;
        const float4 fb = *(const float4*)(fp + 4);
        Af[0] = (__bf16)fa.x; Af[1] = (__bf16)fa.y;
        Af[2] = (__bf16)fa.z; Af[3] = (__bf16)fa.w;
        Af[4] = (__bf16)fb.x; Af[5] = (__bf16)fb.y;
        Af[6] = (__bf16)fb.z; Af[7] = (__bf16)fb.w;
      } else if (g == 1) {
        Af[0] = (__bf16)fp[8];
      }
    }

    // ---- 6 Me-MFMAs, store to LDS (row er'=g*4+r, [d][p], 16-short rows)
#define MEMFMA(Bv, dv, pv, okv)                                              \
    {                                                                        \
      f32x4 a6 = {0.f, 0.f, 0.f, 0.f};                                       \
      a6 = __builtin_amdgcn_mfma_f32_16x16x32_bf16(Af, Bv, a6, 0, 0, 0);     \
      if (okv) {                                                             \
        _Pragma("unroll")                                                    \
        for (int r = 0; r < 4; ++r)                                          \
          mlw[(g * 4 + r) * 144 + dv * 16 + pv] = f2bf(a6[r]);               \
      }                                                                      \
    }
    MEMFMA(Bme0, dT0, pT0, ok0); MEMFMA(Bme1, dT1, pT1, ok1);
    MEMFMA(Bme2, dT2, pT2, ok2); MEMFMA(Bme3, dT3, pT3, ok3);
    MEMFMA(Bme4, dT4, pT4, ok4); MEMFMA(Bme5, dT5, pT5, ok5);
#undef MEMFMA
    __builtin_amdgcn_wave_barrier();

    // ---- message loop over this batch
    for (int il = 0; il < degb; ++il) {
      const int e = __builtin_amdgcn_readlane(esx, il);
      const int s = __builtin_amdgcn_readlane(esy, il);

      const unsigned short* xrp = xbf + (size_t)s * 192 + n16 * 12;
      const uint2 qa = *(const uint2*)xrp;        // x0..x3
      const uint2 qb = *(const uint2*)(xrp + 4);  // x4..x7
      const unsigned int qc = *(const unsigned int*)(xrp + 8);  // x8
      const float x0 = bfLO(qa.x), x1 = bfHI(qa.x);
      const float x2 = bfLO(qa.y), x3 = bfHI(qa.y);
      const float x4 = bfLO(qb.x), x5 = bfHI(qb.x);
      const float x6 = bfLO(qb.y), x7 = bfHI(qb.y);
      const float x8v = bfLO(qc);

      const uint2 wv = *(const uint2*)(w48b + (size_t)e * 64 + n16 * 4);
      const float w0 = bfLO(wv.x);
      const float w1 = bfHI(wv.x);
      const float w2 = bfLO(wv.y);

      const unsigned short* mr = mlw + il * 144 + drow * 16;
      const u32x4 mdv = *(const u32x4*)mr;
      const unsigned int md0 = mdv[0], md1 = mdv[1], md2 = mdv[2], md3 = mdv[3];
      const unsigned int md4 = *(const unsigned int*)(mr + 8);

      bf16x8 A;
      unsigned int B0, B1, B2, B3;
      if (g == 0) {
        A[0] = (__bf16)(x0 * w0); A[1] = (__bf16)(x1 * w0);
        A[2] = (__bf16)(x2 * w0); A[3] = (__bf16)(x3 * w0);
        A[4] = (__bf16)(x4 * w0); A[5] = (__bf16)(x5 * w0);
        A[6] = (__bf16)(x6 * w0); A[7] = (__bf16)(x7 * w0);
        const bool s0 = (Ld == 0);
        B0 = s0 ? md0 : 0u; B1 = s0 ? md1 : 0u;
        B2 = s0 ? md2 : 0u; B3 = s0 ? md3 : 0u;
      } else if (g == 1) {
        A[0] = (__bf16)(x8v * w0); A[1] = (__bf16)(x0 * w1);
        A[2] = (__bf16)(x1 * w1);  A[3] = (__bf16)(x2 * w1);
        A[4] = (__bf16)(x3 * w1);  A[5] = (__bf16)(x4 * w1);
        A[6] = (__bf16)(x5 * w1);  A[7] = (__bf16)(x6 * w1);
        const bool s0 = (Ld == 0), s1 = (Ld == 1);
        B0 = (s0 ? (md4 & 0xffffu) : 0u) | (s1 ? (md0 << 16) : 0u);
        B1 = s1 ? ((md0 >> 16) | (md1 << 16)) : 0u;
        B2 = s1 ? ((md1 >> 16) | (md2 << 16)) : 0u;
        B3 = s1 ? ((md2 >> 16) | (md3 << 16)) : 0u;
      } else if (g == 2) {
        A[0] = (__bf16)(x7 * w1);  A[1] = (__bf16)(x8v * w1);
        A[2] = (__bf16)(x0 * w2);  A[3] = (__bf16)(x1 * w2);
        A[4] = (__bf16)(x2 * w2);  A[5] = (__bf16)(x3 * w2);
        A[6] = (__bf16)(x4 * w2);  A[7] = (__bf16)(x5 * w2);
        const bool s1 = (Ld == 1), s2 = (Ld == 2);
        B0 = s1 ? ((md3 >> 16) | (md4 << 16)) : 0u;
        B1 = s2 ? md0 : 0u; B2 = s2 ? md1 : 0u; B3 = s2 ? md2 : 0u;
      } else {
        A[0] = (__bf16)(x6 * w2); A[1] = (__bf16)(x7 * w2);
        A[2] = (__bf16)(x8v * w2);
        A[3] = (__bf16)0.f; A[4] = (__bf16)0.f; A[5] = (__bf16)0.f;
        A[6] = (__bf16)0.f; A[7] = (__bf16)0.f;
        const bool s2 = (Ld == 2);
        B0 = s2 ? md3 : 0u;
        B1 = s2 ? (md4 & 0xffffu) : 0u;
        B2 = 0u; B3 = 0u;
      }
      u32x4 bv = {B0, B1, B2, B3};
      accm = __builtin_amdgcn_mfma_f32_16x16x32_bf16(
          A, __builtin_bit_cast(bf16x8, bv), accm, 0, 0, 0);
    }
    __builtin_amdgcn_wave_barrier();   // before next batch overwrites LDS
  }

  // ---- write out: C layout col d = lane&15, row m = g*4 + r
  if (dok) {
    float* op = out + (size_t)n * 144 + (g * 4) * 9 + n16;
    op[0]  = accm[0];
    op[9]  = accm[1];
    op[18] = accm[2];
    op[27] = accm[3];
  }
}

// ---------------------------------------------------------------------------
extern "C" void kernel_launch(void* const* d_in, const int* in_sizes, int n_in,
                              void* d_out, int out_size, void* d_ws, size_t ws_size,
                              hipStream_t stream) {
  const float* x      = (const float*)d_in[0];
  const float* filt   = (const float*)d_in[1];
  const float* win    = (const float*)d_in[2];
  const int*   eidx   = (const int*)d_in[3];
  const float* Ux_re  = (const float*)d_in[4];
  const float* Ux_im  = (const float*)d_in[5];
  const float* Uf_re  = (const float*)d_in[6];
  const float* Uf_im  = (const float*)d_in[7];
  const float* Vo_re  = (const float*)d_in[8];
  const float* Vo_im  = (const float*)d_in[9];
  const float* W1     = (const float*)d_in[10];
  const float* W2     = (const float*)d_in[11];
  const float* W3     = (const float*)d_in[12];
  const float* a_w    = (const float*)d_in[13];
  const float* den    = (const float*)d_in[14];
  float* out = (float*)d_out;

  const int N = in_sizes[0] / 144;          // 10000
  const int E = in_sizes[3] / 2;            // 160000
  const int NR = N * 16;                    // x rows (node, m)
  const int* dst = eidx;
  const int* src = eidx + E;

  char* wsb = (char*)d_ws;
  const size_t off_cnt  = 8192;
  const size_t off_slot = off_cnt + 40960;
  const size_t off_w48  = off_slot + (size_t)N * 96 * 8;
  const size_t off_xbf  = off_w48 + (size_t)E * 64 * 2;

  float*          CT    = (float*)wsb;
  int*            cnt   = (int*)(wsb + off_cnt);
  int2*           slot2 = (int2*)(wsb + off_slot);
  unsigned short* w48b  = (unsigned short*)(wsb + off_w48);  // E*64 shorts
  unsigned short* xbf   = (unsigned short*)(wsb + off_xbf);  // NR*12 shorts

  const int nMlp  = E / 256;                // 625
  const int nScat = (E + 255) / 256;        // 625
  const int nXc   = (NR + 255) / 256;       // 625

  hipMemsetAsync(cnt, 0, (size_t)N * sizeof(int), stream);
  prep_kernel<<<nMlp + nScat + nXc + 9, 256, 0, stream>>>(
      win, W1, W2, W3, a_w, den, w48b,
      dst, src, E, cnt, slot2,
      x, NR, xbf,
      Ux_re, Ux_im, Uf_re, Uf_im, Vo_re, Vo_im, CT, nMlp, nScat, nXc);
  node_kernel<<<(N + 3) / 4, 256, 0, stream>>>(
      xbf, filt, cnt, slot2, w48b, CT, out, N);
}

// Round 14
// 92.100 us; speedup vs baseline: 1.5222x; 1.1739x over previous
//
#include <hip/hip_runtime.h>
#include <math.h>

#define PI9 (2.0f * 3.14159265358979323846f / 9.0f)

typedef float f32x4 __attribute__((ext_vector_type(4)));
typedef unsigned short us8 __attribute__((ext_vector_type(8)));
typedef __bf16 bf16x8 __attribute__((ext_vector_type(8)));
typedef unsigned int u32x4 __attribute__((ext_vector_type(4)));

__device__ __forceinline__ float ssp_f(float x) {
  const float ax = fabsf(x);
  const float t = __expf(-ax);
  return fmaxf(x, 0.f) + __logf(1.f + t) - 0.69314718f;
}

__device__ __forceinline__ unsigned short f2bf(float f) {
  unsigned int u = __float_as_uint(f);
  unsigned int r = (u + 0x7FFFu + ((u >> 16) & 1u)) >> 16;
  return (unsigned short)r;
}

__device__ __forceinline__ float bfLO(unsigned int u) {
  return __uint_as_float(u << 16);
}
__device__ __forceinline__ float bfHI(unsigned int u) {
  return __uint_as_float(u & 0xffff0000u);
}

// ===========================================================================
// precompute_C body (9 blocks, one d-slice each) -> CT[d][p][q pad 12]
// ===========================================================================
__device__ void precompute_body(
    int d, unsigned char* smem,
    const float* __restrict__ Ux_re, const float* __restrict__ Ux_im,
    const float* __restrict__ Uf_re, const float* __restrict__ Uf_im,
    const float* __restrict__ Vo_re, const float* __restrict__ Vo_im,
    float* __restrict__ CT) {
  float* G = (float*)smem;                // 2*729 f
  float* TL = (float*)(smem + 5840);      // 729 f
  float* cs9 = (float*)(smem + 8768);
  float* sn9 = (float*)(smem + 8816);
  const int t0 = threadIdx.x;

  if (t0 < 9) {
    float s, c;
    __sincosf(PI9 * (float)t0, &s, &c);
    cs9[t0] = c; sn9[t0] = s;
  }
  __syncthreads();

  for (int t = t0; t < 1458; t += 256) {
    const int which = t / 729, idx = t % 729;
    const int p = idx / 81, ab = idx % 81, a = ab / 9, b = ab % 9;
    const float* Ure = which ? Uf_re : Ux_re;
    const float* Uim = which ? Uf_im : Ux_im;
    float g = 0.f;
#pragma unroll
    for (int v = 0; v < 3; ++v) {
      const int uc = v + 2;
      float hre = 0.f, him = 0.f;
#pragma unroll
      for (int ui = 0; ui < 5; ++ui) {
        const int u = (ui + 7) % 9;
        const float re = Ure[p * 25 + ui * 5 + uc];
        const float im = Uim[p * 25 + ui * 5 + uc];
        const int k = (u * a) % 9;
        const float c = cs9[k], s = sn9[k];
        hre += re * c - im * s;
        him += re * s + im * c;
      }
      hre *= (1.f / 9.f); him *= (1.f / 9.f);
      if (v == 0) {
        g += hre;
      } else {
        const int k = (v * b) % 9;
        g += 2.f * (hre * cs9[k] - him * sn9[k]);
      }
    }
    G[which * 729 + p * 81 + ab] = g * (1.f / 9.f);
  }
  __syncthreads();

  for (int t = t0; t < 729; t += 256) {
    const int ab = t / 9, dd = t % 9, a = ab / 9, b = ab % 9;
    float acc = 0.f;
    for (int u = 0; u < 9; ++u)
      for (int v = 0; v < 5; ++v) {
        const int k = (u * a + v * b) % 9;
        acc += Vo_re[u * 45 + v * 9 + dd] * cs9[k]
             + Vo_im[u * 45 + v * 9 + dd] * sn9[k];
      }
    TL[ab * 9 + dd] = acc;
  }
  __syncthreads();

  if (t0 < 108) {
    const int p = t0 / 12, q = t0 % 12;
    float acc = 0.f;
    if (q < 9) {
      for (int ab = 0; ab < 81; ++ab)
        acc += G[p * 81 + ab] * G[729 + q * 81 + ab] * TL[ab * 9 + d];
    }
    CT[(d * 9 + p) * 12 + q] = acc;
  }
}

// ===========================================================================
// MLP body (2 reps = 128 edges / block); output w48T bf16 [e][Ld(4)][m(16)]
// ===========================================================================
__device__ void mlp_body(
    int mblk, unsigned char* smem, const float* __restrict__ win,
    const float* __restrict__ W1, const float* __restrict__ W2,
    const float* __restrict__ W3, const float* __restrict__ a_w,
    const float* __restrict__ den, unsigned short* __restrict__ w48b) {
  float* W1s = (float*)smem;                              // 2048 B
  unsigned short* W2T = (unsigned short*)(smem + 2048);   // 8192 B
  unsigned short* W3T = (unsigned short*)(smem + 10240);  // 6144 B
  unsigned short* H1 = (unsigned short*)(smem + 16384);   // 8192 B
  unsigned short* H2 = (unsigned short*)(smem + 24576);   // 8192 B
  const int t = threadIdx.x;

  const float invden = 1.f / den[0];
  const float sc0 = a_w[0] * invden, sc1 = a_w[10] * invden, sc2 = a_w[22] * invden;
  const float rs8 = 0.35355339059327373f;

  if (t < 128) {
    float4 v = ((const float4*)W1)[t];
    v.x *= rs8; v.y *= rs8; v.z *= rs8; v.w *= rs8;
    ((float4*)W1s)[t] = v;
  }
  for (int i = t; i < 4096; i += 256) {
    const int k = i >> 6, j = i & 63;
    W2T[j * 64 + ((((k >> 3) ^ (j & 7)) << 3)) + (k & 7)] = f2bf(W2[i] * 0.125f);
  }
  for (int i = t; i < 3072; i += 256) {
    const int k = i / 48, j = i % 48;
    const int jm = j % 3;
    const float s = (jm == 0) ? sc0 : ((jm == 1) ? sc1 : sc2);
    W3T[j * 64 + ((((k >> 3) ^ (j & 7)) << 3)) + (k & 7)] = f2bf(W3[i] * 0.125f * s);
  }
  __syncthreads();

  const int w = t >> 6, l = t & 63;
  const int er = l & 15, g = l >> 4;
  unsigned short* h1p = H1 + w * 1024;
  unsigned short* h2p = H2 + w * 1024;

#pragma unroll 1
  for (int rep = 0; rep < 2; ++rep) {
    const int e = mblk * 128 + rep * 64 + w * 16 + er;

    float in8[8];
    {
      const float4 A = *(const float4*)(win + (size_t)e * 8);
      const float4 B = *(const float4*)(win + (size_t)e * 8 + 4);
      in8[0] = A.x; in8[1] = A.y; in8[2] = A.z; in8[3] = A.w;
      in8[4] = B.x; in8[5] = B.y; in8[6] = B.z; in8[7] = B.w;
    }
    float h[16];
#pragma unroll
    for (int c = 0; c < 16; ++c) h[c] = 0.f;
#pragma unroll
    for (int k = 0; k < 8; ++k) {
      const float* wr = &W1s[k * 64 + g * 16];
      const float4 w0 = *(const float4*)wr;
      const float4 w1 = *(const float4*)(wr + 4);
      const float4 w2 = *(const float4*)(wr + 8);
      const float4 w3 = *(const float4*)(wr + 12);
      const float ik = in8[k];
      h[0]  = fmaf(ik, w0.x, h[0]);  h[1]  = fmaf(ik, w0.y, h[1]);
      h[2]  = fmaf(ik, w0.z, h[2]);  h[3]  = fmaf(ik, w0.w, h[3]);
      h[4]  = fmaf(ik, w1.x, h[4]);  h[5]  = fmaf(ik, w1.y, h[5]);
      h[6]  = fmaf(ik, w1.z, h[6]);  h[7]  = fmaf(ik, w1.w, h[7]);
      h[8]  = fmaf(ik, w2.x, h[8]);  h[9]  = fmaf(ik, w2.y, h[9]);
      h[10] = fmaf(ik, w2.z, h[10]); h[11] = fmaf(ik, w2.w, h[11]);
      h[12] = fmaf(ik, w3.x, h[12]); h[13] = fmaf(ik, w3.y, h[13]);
      h[14] = fmaf(ik, w3.z, h[14]); h[15] = fmaf(ik, w3.w, h[15]);
    }
    us8 pk0, pk1;
#pragma unroll
    for (int jj = 0; jj < 8; ++jj) pk0[jj] = f2bf(ssp_f(h[jj]));
#pragma unroll
    for (int jj = 0; jj < 8; ++jj) pk1[jj] = f2bf(ssp_f(h[8 + jj]));
    *(us8*)&h1p[er * 64 + (((2 * g) ^ (er & 7)) << 3)] = pk0;
    *(us8*)&h1p[er * 64 + (((2 * g + 1) ^ (er & 7)) << 3)] = pk1;
    __builtin_amdgcn_wave_barrier();

    const us8 a0 = *(const us8*)&h1p[er * 64 + ((g ^ (er & 7)) << 3)];
    const us8 a1 = *(const us8*)&h1p[er * 64 + (((g + 4) ^ (er & 7)) << 3)];
    float hh[16];
#pragma unroll
    for (int nt = 0; nt < 4; ++nt) {
      const int j = nt * 16 + er;
      const us8 b0 = *(const us8*)&W2T[j * 64 + ((g ^ (j & 7)) << 3)];
      const us8 b1 = *(const us8*)&W2T[j * 64 + (((g + 4) ^ (j & 7)) << 3)];
      f32x4 acc = {0.f, 0.f, 0.f, 0.f};
      acc = __builtin_amdgcn_mfma_f32_16x16x32_bf16(
          __builtin_bit_cast(bf16x8, a0), __builtin_bit_cast(bf16x8, b0), acc, 0, 0, 0);
      acc = __builtin_amdgcn_mfma_f32_16x16x32_bf16(
          __builtin_bit_cast(bf16x8, a1), __builtin_bit_cast(bf16x8, b1), acc, 0, 0, 0);
#pragma unroll
      for (int r = 0; r < 4; ++r) hh[nt * 4 + r] = ssp_f(acc[r]);
    }
#pragma unroll
    for (int nt = 0; nt < 4; ++nt)
#pragma unroll
      for (int r = 0; r < 4; ++r) {
        const int e2 = g * 4 + r;
        const int k2 = nt * 16 + er;
        h2p[e2 * 64 + ((((k2 >> 3) ^ (e2 & 7)) << 3)) + (k2 & 7)] = f2bf(hh[nt * 4 + r]);
      }
    __builtin_amdgcn_wave_barrier();

    const us8 c0 = *(const us8*)&h2p[er * 64 + ((g ^ (er & 7)) << 3)];
    const us8 c1 = *(const us8*)&h2p[er * 64 + (((g + 4) ^ (er & 7)) << 3)];
    const int ebase = mblk * 128 + rep * 64 + w * 16 + g * 4;
#pragma unroll
    for (int nt = 0; nt < 3; ++nt) {
      const int o = nt * 16 + er;
      const int om = o / 3, ol = o - om * 3;
      const us8 b0 = *(const us8*)&W3T[o * 64 + ((g ^ (o & 7)) << 3)];
      const us8 b1 = *(const us8*)&W3T[o * 64 + (((g + 4) ^ (o & 7)) << 3)];
      f32x4 acc = {0.f, 0.f, 0.f, 0.f};
      acc = __builtin_amdgcn_mfma_f32_16x16x32_bf16(
          __builtin_bit_cast(bf16x8, c0), __builtin_bit_cast(bf16x8, b0), acc, 0, 0, 0);
      acc = __builtin_amdgcn_mfma_f32_16x16x32_bf16(
          __builtin_bit_cast(bf16x8, c1), __builtin_bit_cast(bf16x8, b1), acc, 0, 0, 0);
      // layout: [e][ol(Ld)][om(m)]
#pragma unroll
      for (int r = 0; r < 4; ++r)
        w48b[(size_t)(ebase + r) * 64 + ol * 16 + om] = f2bf(acc[r]);
    }
    __builtin_amdgcn_wave_barrier();
  }
}

// ===========================================================================
// prep: [0,nMlp) MLP | [+nScat) scatter | [+nXc) x->bf16 pad12 | [+9) CT
// ===========================================================================
__global__ __launch_bounds__(256) void prep_kernel(
    const float* __restrict__ win, const float* __restrict__ W1,
    const float* __restrict__ W2, const float* __restrict__ W3,
    const float* __restrict__ a_w, const float* __restrict__ den,
    unsigned short* __restrict__ w48b,
    const int* __restrict__ dst, const int* __restrict__ src, int E,
    int* __restrict__ cnt, int2* __restrict__ slots2,
    const float* __restrict__ xsrc, int NR, unsigned short* __restrict__ xbf,
    const float* __restrict__ Ux_re, const float* __restrict__ Ux_im,
    const float* __restrict__ Uf_re, const float* __restrict__ Uf_im,
    const float* __restrict__ Vo_re, const float* __restrict__ Vo_im,
    float* __restrict__ CT, int nMlp, int nScat, int nXc) {
  __shared__ __align__(16) unsigned char smem[32768];
  const int bid = blockIdx.x;
  if (bid < nMlp) {
    mlp_body(bid, smem, win, W1, W2, W3, a_w, den, w48b);
  } else if (bid < nMlp + nScat) {
    const int e = (bid - nMlp) * 256 + threadIdx.x;
    if (e < E) {
      const int d = dst[e];
      const int pos = atomicAdd(&cnt[d], 1);
      if (pos < 96) slots2[(size_t)d * 96 + pos] = make_int2(e, src[e]);
    }
  } else if (bid < nMlp + nScat + nXc) {
    const int r = (bid - nMlp - nScat) * 256 + threadIdx.x;
    if (r < NR) {
      const float* xp = xsrc + (size_t)r * 9;
      unsigned int u0 = (unsigned)f2bf(xp[0]) | ((unsigned)f2bf(xp[1]) << 16);
      unsigned int u1 = (unsigned)f2bf(xp[2]) | ((unsigned)f2bf(xp[3]) << 16);
      unsigned int u2 = (unsigned)f2bf(xp[4]) | ((unsigned)f2bf(xp[5]) << 16);
      unsigned int u3 = (unsigned)f2bf(xp[6]) | ((unsigned)f2bf(xp[7]) << 16);
      unsigned int u4 = (unsigned)f2bf(xp[8]);
      unsigned short* op = xbf + (size_t)r * 12;
      *(uint2*)op = make_uint2(u0, u1);
      *(uint2*)(op + 4) = make_uint2(u2, u3);
      *(uint2*)(op + 8) = make_uint2(u4, 0u);
    }
  } else {
    precompute_body(bid - nMlp - nScat - nXc, smem, Ux_re, Ux_im, Uf_re,
                    Uf_im, Vo_re, Vo_im, CT);
  }
}

// ===========================================================================
// Node kernel v13: wave-per-node, fused Me (unchanged), NEW message MFMA:
//   C1[m,d] = sum_p x[s][m,p] * Me[p,d]   (A,B = raw packed dwords, k=p<=8,
//   only g0/g1 lanes carry data -> branch-free cndmask operand build)
//   acc[m,d] += C1[m,d] * w48T[e][Ld(d)][m]   (4 FMAs; one 8B w load)
// ===========================================================================
__global__ __launch_bounds__(256) void node_kernel(
    const unsigned short* __restrict__ xbf, const float* __restrict__ filt,
    const int* __restrict__ cnt, const int2* __restrict__ slots2,
    const unsigned short* __restrict__ w48b, const float* __restrict__ CT,
    float* __restrict__ out, int N) {
  __shared__ __align__(16) unsigned short meL[4][2304];  // il*144 + d*16 + p
  const int t = threadIdx.x, w = t >> 6, l = t & 63;
  const int n16 = l & 15, g = l >> 4;
  const int Ld = (n16 == 0) ? 0 : ((n16 < 4) ? 1 : 2);
  const bool dok = n16 < 9;
  const int drow = dok ? n16 : 0;
  const bool isg0 = (g == 0), isg1 = (g == 1);
  const int n = blockIdx.x * 4 + w;
  if (n >= N) return;

  // ---- per-lane constant: Me-MFMA B-frags (6 tiles) + (d,p) of my col/tile
  int dT0, pT0, dT1, pT1, dT2, pT2, dT3, pT3, dT4, pT4, dT5, pT5;
  bool ok0, ok1, ok2, ok3, ok4, ok5;
  bf16x8 Bme0, Bme1, Bme2, Bme3, Bme4, Bme5;
#define MKB(tt, Bv, dv, pv, okv)                                             \
  {                                                                          \
    const int col = tt * 16 + n16;                                           \
    okv = (col < 81);                                                        \
    dv = okv ? col / 9 : 0;                                                  \
    pv = okv ? col % 9 : 0;                                                  \
    bf16x8 bv;                                                               \
    _Pragma("unroll")                                                        \
    for (int j = 0; j < 8; ++j) bv[j] = (__bf16)0.f;                         \
    if (okv) {                                                               \
      const float* cp = CT + col * 12;                                       \
      if (g == 0) {                                                          \
        const float4 ca = *(const float4*)cp;                                \
        const float4 cb = *(const float4*)(cp + 4);                          \
        bv[0] = (__bf16)ca.x; bv[1] = (__bf16)ca.y;                          \
        bv[2] = (__bf16)ca.z; bv[3] = (__bf16)ca.w;                          \
        bv[4] = (__bf16)cb.x; bv[5] = (__bf16)cb.y;                          \
        bv[6] = (__bf16)cb.z; bv[7] = (__bf16)cb.w;                          \
      } else if (g == 1) {                                                   \
        bv[0] = (__bf16)cp[8];                                               \
      }                                                                      \
    }                                                                        \
    Bv = bv;                                                                 \
  }
  MKB(0, Bme0, dT0, pT0, ok0); MKB(1, Bme1, dT1, pT1, ok1);
  MKB(2, Bme2, dT2, pT2, ok2); MKB(3, Bme3, dT3, pT3, ok3);
  MKB(4, Bme4, dT4, pT4, ok4); MKB(5, Bme5, dT5, pT5, ok5);
#undef MKB

  int deg = cnt[n];
  if (deg > 96) deg = 96;
  const int2* sl2 = slots2 + (size_t)n * 96;
  unsigned short* mlw = &meL[w][0];

  f32x4 accm = {0.f, 0.f, 0.f, 0.f};

  const int nb = (deg + 15) >> 4;
  for (int b = 0; b < nb; ++b) {
    const int base = b * 16;
    const int degb = (deg - base < 16) ? (deg - base) : 16;

    // ---- batch edge list into lanes (er holds edge er) + Me A-frag
    int esx = 0, esy = 0;
    if (n16 < degb) {
      const int2 v = sl2[base + n16];
      esx = v.x; esy = v.y;
    }
    bf16x8 Af;
#pragma unroll
    for (int j = 0; j < 8; ++j) Af[j] = (__bf16)0.f;
    if (n16 < degb) {
      const float* fp = filt + (size_t)esx * 9;
      if (g == 0) {
        const float4 fa = *(const float4*)fp;
        const float4 fb = *(const float4*)(fp + 4);
        Af[0] = (__bf16)fa.x; Af[1] = (__bf16)fa.y;
        Af[2] = (__bf16)fa.z; Af[3] = (__bf16)fa.w;
        Af[4] = (__bf16)fb.x; Af[5] = (__bf16)fb.y;
        Af[6] = (__bf16)fb.z; Af[7] = (__bf16)fb.w;
      } else if (g == 1) {
        Af[0] = (__bf16)fp[8];
      }
    }

    // ---- 6 Me-MFMAs, store to LDS (row er'=g*4+r, [d][p], 16-short rows)
#define MEMFMA(Bv, dv, pv, okv)                                              \
    {                                                                        \
      f32x4 a6 = {0.f, 0.f, 0.f, 0.f};                                       \
      a6 = __builtin_amdgcn_mfma_f32_16x16x32_bf16(Af, Bv, a6, 0, 0, 0);     \
      if (okv) {                                                             \
        _Pragma("unroll")                                                    \
        for (int r = 0; r < 4; ++r)                                          \
          mlw[(g * 4 + r) * 144 + dv * 16 + pv] = f2bf(a6[r]);               \
      }                                                                      \
    }
    MEMFMA(Bme0, dT0, pT0, ok0); MEMFMA(Bme1, dT1, pT1, ok1);
    MEMFMA(Bme2, dT2, pT2, ok2); MEMFMA(Bme3, dT3, pT3, ok3);
    MEMFMA(Bme4, dT4, pT4, ok4); MEMFMA(Bme5, dT5, pT5, ok5);
#undef MEMFMA
    __builtin_amdgcn_wave_barrier();

    // ---- message loop: branch-free operands, 1 MFMA + 4 FMA per edge
    for (int il = 0; il < degb; ++il) {
      const int e = __builtin_amdgcn_readlane(esx, il);
      const int s = __builtin_amdgcn_readlane(esy, il);

      const unsigned short* xrp = xbf + (size_t)s * 192 + n16 * 12;
      const u32x4 q = *(const u32x4*)xrp;                        // x0..x7
      const unsigned int qc = *(const unsigned int*)(xrp + 8);   // {x8, 0}

      const uint2 wv =
          *(const uint2*)(w48b + (size_t)e * 64 + Ld * 16 + g * 4);

      const unsigned short* mr = mlw + il * 144 + drow * 16;
      const u32x4 mdv = *(const u32x4*)mr;
      const unsigned int md4 = (*(const unsigned int*)(mr + 8)) & 0xffffu;

      u32x4 av;
      av[0] = isg0 ? q[0] : (isg1 ? qc : 0u);
      av[1] = isg0 ? q[1] : 0u;
      av[2] = isg0 ? q[2] : 0u;
      av[3] = isg0 ? q[3] : 0u;
      u32x4 bv;
      bv[0] = isg0 ? mdv[0] : (isg1 ? md4 : 0u);
      bv[1] = isg0 ? mdv[1] : 0u;
      bv[2] = isg0 ? mdv[2] : 0u;
      bv[3] = isg0 ? mdv[3] : 0u;

      f32x4 c1 = {0.f, 0.f, 0.f, 0.f};
      c1 = __builtin_amdgcn_mfma_f32_16x16x32_bf16(
          __builtin_bit_cast(bf16x8, av), __builtin_bit_cast(bf16x8, bv),
          c1, 0, 0, 0);
      accm[0] = fmaf(c1[0], bfLO(wv.x), accm[0]);
      accm[1] = fmaf(c1[1], bfHI(wv.x), accm[1]);
      accm[2] = fmaf(c1[2], bfLO(wv.y), accm[2]);
      accm[3] = fmaf(c1[3], bfHI(wv.y), accm[3]);
    }
    __builtin_amdgcn_wave_barrier();   // before next batch overwrites LDS
  }

  // ---- write out: C layout col d = lane&15, row m = g*4 + r
  if (dok) {
    float* op = out + (size_t)n * 144 + (g * 4) * 9 + n16;
    op[0]  = accm[0];
    op[9]  = accm[1];
    op[18] = accm[2];
    op[27] = accm[3];
  }
}

// ---------------------------------------------------------------------------
extern "C" void kernel_launch(void* const* d_in, const int* in_sizes, int n_in,
                              void* d_out, int out_size, void* d_ws, size_t ws_size,
                              hipStream_t stream) {
  const float* x      = (const float*)d_in[0];
  const float* filt   = (const float*)d_in[1];
  const float* win    = (const float*)d_in[2];
  const int*   eidx   = (const int*)d_in[3];
  const float* Ux_re  = (const float*)d_in[4];
  const float* Ux_im  = (const float*)d_in[5];
  const float* Uf_re  = (const float*)d_in[6];
  const float* Uf_im  = (const float*)d_in[7];
  const float* Vo_re  = (const float*)d_in[8];
  const float* Vo_im  = (const float*)d_in[9];
  const float* W1     = (const float*)d_in[10];
  const float* W2     = (const float*)d_in[11];
  const float* W3     = (const float*)d_in[12];
  const float* a_w    = (const float*)d_in[13];
  const float* den    = (const float*)d_in[14];
  float* out = (float*)d_out;

  const int N = in_sizes[0] / 144;          // 10000
  const int E = in_sizes[3] / 2;            // 160000
  const int NR = N * 16;                    // x rows (node, m)
  const int* dst = eidx;
  const int* src = eidx + E;

  char* wsb = (char*)d_ws;
  const size_t off_cnt  = 8192;
  const size_t off_slot = off_cnt + 40960;
  const size_t off_w48  = off_slot + (size_t)N * 96 * 8;
  const size_t off_xbf  = off_w48 + (size_t)E * 64 * 2;

  float*          CT    = (float*)wsb;
  int*            cnt   = (int*)(wsb + off_cnt);
  int2*           slot2 = (int2*)(wsb + off_slot);
  unsigned short* w48b  = (unsigned short*)(wsb + off_w48);  // E*64 shorts
  unsigned short* xbf   = (unsigned short*)(wsb + off_xbf);  // NR*12 shorts

  const int nMlp  = E / 128;                // 1250
  const int nScat = (E + 255) / 256;        // 625
  const int nXc   = (NR + 255) / 256;       // 625

  hipMemsetAsync(cnt, 0, (size_t)N * sizeof(int), stream);
  prep_kernel<<<nMlp + nScat + nXc + 9, 256, 0, stream>>>(
      win, W1, W2, W3, a_w, den, w48b,
      dst, src, E, cnt, slot2,
      x, NR, xbf,
      Ux_re, Ux_im, Uf_re, Uf_im, Vo_re, Vo_im, CT, nMlp, nScat, nXc);
  node_kernel<<<(N + 3) / 4, 256, 0, stream>>>(
      xbf, filt, cnt, slot2, w48b, CT, out, N);
}

// Round 15
// 88.994 us; speedup vs baseline: 1.5753x; 1.0349x over previous
//
#include <hip/hip_runtime.h>
#include <math.h>

#define PI9 (2.0f * 3.14159265358979323846f / 9.0f)

typedef float f32x4 __attribute__((ext_vector_type(4)));
typedef unsigned short us8 __attribute__((ext_vector_type(8)));
typedef __bf16 bf16x8 __attribute__((ext_vector_type(8)));
typedef unsigned int u32x4 __attribute__((ext_vector_type(4)));

__device__ __forceinline__ float ssp_f(float x) {
  const float ax = fabsf(x);
  const float t = __expf(-ax);
  return fmaxf(x, 0.f) + __logf(1.f + t) - 0.69314718f;
}

__device__ __forceinline__ unsigned short f2bf(float f) {
  unsigned int u = __float_as_uint(f);
  unsigned int r = (u + 0x7FFFu + ((u >> 16) & 1u)) >> 16;
  return (unsigned short)r;
}

__device__ __forceinline__ float bfLO(unsigned int u) {
  return __uint_as_float(u << 16);
}
__device__ __forceinline__ float bfHI(unsigned int u) {
  return __uint_as_float(u & 0xffff0000u);
}

// ===========================================================================
// wconv: one-time weight conversion (scaled f32 W1s; bf16 pre-swizzled
// W2T/W3T) so MLP blocks never stage weights.
// ===========================================================================
__global__ __launch_bounds__(256) void wconv_kernel(
    const float* __restrict__ W1, const float* __restrict__ W2,
    const float* __restrict__ W3, const float* __restrict__ a_w,
    const float* __restrict__ den, float* __restrict__ W1s,
    unsigned short* __restrict__ W2T, unsigned short* __restrict__ W3T) {
  const int i = blockIdx.x * 256 + threadIdx.x;
  const float invden = 1.f / den[0];
  const float sc0 = a_w[0] * invden, sc1 = a_w[10] * invden, sc2 = a_w[22] * invden;
  const float rs8 = 0.35355339059327373f;
  if (i < 512) {
    W1s[i] = W1[i] * rs8;
  } else if (i < 4608) {
    const int ii = i - 512;
    const int k = ii >> 6, j = ii & 63;
    W2T[j * 64 + ((((k >> 3) ^ (j & 7)) << 3)) + (k & 7)] = f2bf(W2[ii] * 0.125f);
  } else if (i < 7680) {
    const int ii = i - 4608;
    const int k = ii / 48, j = ii % 48;
    const int jm = j % 3;
    const float s = (jm == 0) ? sc0 : ((jm == 1) ? sc1 : sc2);
    W3T[j * 64 + ((((k >> 3) ^ (j & 7)) << 3)) + (k & 7)] = f2bf(W3[ii] * 0.125f * s);
  }
}

// ===========================================================================
// precompute_C body (9 blocks, one d-slice each) -> CT[d][p][q pad 12]
// ===========================================================================
__device__ void precompute_body(
    int d, unsigned char* smem,
    const float* __restrict__ Ux_re, const float* __restrict__ Ux_im,
    const float* __restrict__ Uf_re, const float* __restrict__ Uf_im,
    const float* __restrict__ Vo_re, const float* __restrict__ Vo_im,
    float* __restrict__ CT) {
  float* G = (float*)smem;                // 2*729 f
  float* TL = (float*)(smem + 5840);      // 729 f
  float* cs9 = (float*)(smem + 8768);
  float* sn9 = (float*)(smem + 8816);
  const int t0 = threadIdx.x;

  if (t0 < 9) {
    float s, c;
    __sincosf(PI9 * (float)t0, &s, &c);
    cs9[t0] = c; sn9[t0] = s;
  }
  __syncthreads();

  for (int t = t0; t < 1458; t += 256) {
    const int which = t / 729, idx = t % 729;
    const int p = idx / 81, ab = idx % 81, a = ab / 9, b = ab % 9;
    const float* Ure = which ? Uf_re : Ux_re;
    const float* Uim = which ? Uf_im : Ux_im;
    float g = 0.f;
#pragma unroll
    for (int v = 0; v < 3; ++v) {
      const int uc = v + 2;
      float hre = 0.f, him = 0.f;
#pragma unroll
      for (int ui = 0; ui < 5; ++ui) {
        const int u = (ui + 7) % 9;
        const float re = Ure[p * 25 + ui * 5 + uc];
        const float im = Uim[p * 25 + ui * 5 + uc];
        const int k = (u * a) % 9;
        const float c = cs9[k], s = sn9[k];
        hre += re * c - im * s;
        him += re * s + im * c;
      }
      hre *= (1.f / 9.f); him *= (1.f / 9.f);
      if (v == 0) {
        g += hre;
      } else {
        const int k = (v * b) % 9;
        g += 2.f * (hre * cs9[k] - him * sn9[k]);
      }
    }
    G[which * 729 + p * 81 + ab] = g * (1.f / 9.f);
  }
  __syncthreads();

  for (int t = t0; t < 729; t += 256) {
    const int ab = t / 9, dd = t % 9, a = ab / 9, b = ab % 9;
    float acc = 0.f;
    for (int u = 0; u < 9; ++u)
      for (int v = 0; v < 5; ++v) {
        const int k = (u * a + v * b) % 9;
        acc += Vo_re[u * 45 + v * 9 + dd] * cs9[k]
             + Vo_im[u * 45 + v * 9 + dd] * sn9[k];
      }
    TL[ab * 9 + dd] = acc;
  }
  __syncthreads();

  if (t0 < 108) {
    const int p = t0 / 12, q = t0 % 12;
    float acc = 0.f;
    if (q < 9) {
      for (int ab = 0; ab < 81; ++ab)
        acc += G[p * 81 + ab] * G[729 + q * 81 + ab] * TL[ab * 9 + d];
    }
    CT[(d * 9 + p) * 12 + q] = acc;
  }
}

// ===========================================================================
// MLP body (2 reps = 128 edges / block); weights from GLOBAL (L1-resident);
// LDS only H1/H2 (16 KB).  Output w48T bf16 [e][Ld(4)][m(16)].
// ===========================================================================
__device__ void mlp_body(
    int mblk, unsigned char* smem, const float* __restrict__ win,
    const float* __restrict__ W1s, const unsigned short* __restrict__ W2T,
    const unsigned short* __restrict__ W3T,
    unsigned short* __restrict__ w48b) {
  unsigned short* H1 = (unsigned short*)smem;            // 8192 B
  unsigned short* H2 = (unsigned short*)(smem + 8192);   // 8192 B
  const int t = threadIdx.x;
  const int w = t >> 6, l = t & 63;
  const int er = l & 15, g = l >> 4;
  unsigned short* h1p = H1 + w * 1024;
  unsigned short* h2p = H2 + w * 1024;

#pragma unroll 1
  for (int rep = 0; rep < 2; ++rep) {
    const int e = mblk * 128 + rep * 64 + w * 16 + er;

    float in8[8];
    {
      const float4 A = *(const float4*)(win + (size_t)e * 8);
      const float4 B = *(const float4*)(win + (size_t)e * 8 + 4);
      in8[0] = A.x; in8[1] = A.y; in8[2] = A.z; in8[3] = A.w;
      in8[4] = B.x; in8[5] = B.y; in8[6] = B.z; in8[7] = B.w;
    }
    float h[16];
#pragma unroll
    for (int c = 0; c < 16; ++c) h[c] = 0.f;
#pragma unroll
    for (int k = 0; k < 8; ++k) {
      const float* wr = W1s + k * 64 + g * 16;
      const float4 w0 = *(const float4*)wr;
      const float4 w1 = *(const float4*)(wr + 4);
      const float4 w2 = *(const float4*)(wr + 8);
      const float4 w3 = *(const float4*)(wr + 12);
      const float ik = in8[k];
      h[0]  = fmaf(ik, w0.x, h[0]);  h[1]  = fmaf(ik, w0.y, h[1]);
      h[2]  = fmaf(ik, w0.z, h[2]);  h[3]  = fmaf(ik, w0.w, h[3]);
      h[4]  = fmaf(ik, w1.x, h[4]);  h[5]  = fmaf(ik, w1.y, h[5]);
      h[6]  = fmaf(ik, w1.z, h[6]);  h[7]  = fmaf(ik, w1.w, h[7]);
      h[8]  = fmaf(ik, w2.x, h[8]);  h[9]  = fmaf(ik, w2.y, h[9]);
      h[10] = fmaf(ik, w2.z, h[10]); h[11] = fmaf(ik, w2.w, h[11]);
      h[12] = fmaf(ik, w3.x, h[12]); h[13] = fmaf(ik, w3.y, h[13]);
      h[14] = fmaf(ik, w3.z, h[14]); h[15] = fmaf(ik, w3.w, h[15]);
    }
    us8 pk0, pk1;
#pragma unroll
    for (int jj = 0; jj < 8; ++jj) pk0[jj] = f2bf(ssp_f(h[jj]));
#pragma unroll
    for (int jj = 0; jj < 8; ++jj) pk1[jj] = f2bf(ssp_f(h[8 + jj]));
    *(us8*)&h1p[er * 64 + (((2 * g) ^ (er & 7)) << 3)] = pk0;
    *(us8*)&h1p[er * 64 + (((2 * g + 1) ^ (er & 7)) << 3)] = pk1;
    __builtin_amdgcn_wave_barrier();

    const us8 a0 = *(const us8*)&h1p[er * 64 + ((g ^ (er & 7)) << 3)];
    const us8 a1 = *(const us8*)&h1p[er * 64 + (((g + 4) ^ (er & 7)) << 3)];
    float hh[16];
#pragma unroll
    for (int nt = 0; nt < 4; ++nt) {
      const int j = nt * 16 + er;
      const us8 b0 = *(const us8*)&W2T[j * 64 + ((g ^ (j & 7)) << 3)];
      const us8 b1 = *(const us8*)&W2T[j * 64 + (((g + 4) ^ (j & 7)) << 3)];
      f32x4 acc = {0.f, 0.f, 0.f, 0.f};
      acc = __builtin_amdgcn_mfma_f32_16x16x32_bf16(
          __builtin_bit_cast(bf16x8, a0), __builtin_bit_cast(bf16x8, b0), acc, 0, 0, 0);
      acc = __builtin_amdgcn_mfma_f32_16x16x32_bf16(
          __builtin_bit_cast(bf16x8, a1), __builtin_bit_cast(bf16x8, b1), acc, 0, 0, 0);
#pragma unroll
      for (int r = 0; r < 4; ++r) hh[nt * 4 + r] = ssp_f(acc[r]);
    }
#pragma unroll
    for (int nt = 0; nt < 4; ++nt)
#pragma unroll
      for (int r = 0; r < 4; ++r) {
        const int e2 = g * 4 + r;
        const int k2 = nt * 16 + er;
        h2p[e2 * 64 + ((((k2 >> 3) ^ (e2 & 7)) << 3)) + (k2 & 7)] = f2bf(hh[nt * 4 + r]);
      }
    __builtin_amdgcn_wave_barrier();

    const us8 c0 = *(const us8*)&h2p[er * 64 + ((g ^ (er & 7)) << 3)];
    const us8 c1 = *(const us8*)&h2p[er * 64 + (((g + 4) ^ (er & 7)) << 3)];
    const int ebase = mblk * 128 + rep * 64 + w * 16 + g * 4;
#pragma unroll
    for (int nt = 0; nt < 3; ++nt) {
      const int o = nt * 16 + er;
      const int om = o / 3, ol = o - om * 3;
      const us8 b0 = *(const us8*)&W3T[o * 64 + ((g ^ (o & 7)) << 3)];
      const us8 b1 = *(const us8*)&W3T[o * 64 + (((g + 4) ^ (o & 7)) << 3)];
      f32x4 acc = {0.f, 0.f, 0.f, 0.f};
      acc = __builtin_amdgcn_mfma_f32_16x16x32_bf16(
          __builtin_bit_cast(bf16x8, c0), __builtin_bit_cast(bf16x8, b0), acc, 0, 0, 0);
      acc = __builtin_amdgcn_mfma_f32_16x16x32_bf16(
          __builtin_bit_cast(bf16x8, c1), __builtin_bit_cast(bf16x8, b1), acc, 0, 0, 0);
      // layout: [e][ol(Ld)][om(m)]
#pragma unroll
      for (int r = 0; r < 4; ++r)
        w48b[(size_t)(ebase + r) * 64 + ol * 16 + om] = f2bf(acc[r]);
    }
    __builtin_amdgcn_wave_barrier();
  }
}

// ===========================================================================
// prep: [0,9) CT | [+nScat) scatter | [+nXc) x->bf16 pad12 | [+nMlp) MLP
// (CT first so the long-pole starts at t=0)
// ===========================================================================
__global__ __launch_bounds__(256) void prep_kernel(
    const float* __restrict__ win, const float* __restrict__ W1s,
    const unsigned short* __restrict__ W2T,
    const unsigned short* __restrict__ W3T,
    unsigned short* __restrict__ w48b,
    const int* __restrict__ dst, const int* __restrict__ src, int E,
    int* __restrict__ cnt, int2* __restrict__ slots2,
    const float* __restrict__ xsrc, int NR, unsigned short* __restrict__ xbf,
    const float* __restrict__ Ux_re, const float* __restrict__ Ux_im,
    const float* __restrict__ Uf_re, const float* __restrict__ Uf_im,
    const float* __restrict__ Vo_re, const float* __restrict__ Vo_im,
    float* __restrict__ CT, int nScat, int nXc) {
  __shared__ __align__(16) unsigned char smem[16384];
  const int bid = blockIdx.x;
  if (bid < 9) {
    precompute_body(bid, smem, Ux_re, Ux_im, Uf_re, Uf_im, Vo_re, Vo_im, CT);
  } else if (bid < 9 + nScat) {
    const int e = (bid - 9) * 256 + threadIdx.x;
    if (e < E) {
      const int d = dst[e];
      const int pos = atomicAdd(&cnt[d], 1);
      if (pos < 96) slots2[(size_t)d * 96 + pos] = make_int2(e, src[e]);
    }
  } else if (bid < 9 + nScat + nXc) {
    const int r = (bid - 9 - nScat) * 256 + threadIdx.x;
    if (r < NR) {
      const float* xp = xsrc + (size_t)r * 9;
      unsigned int u0 = (unsigned)f2bf(xp[0]) | ((unsigned)f2bf(xp[1]) << 16);
      unsigned int u1 = (unsigned)f2bf(xp[2]) | ((unsigned)f2bf(xp[3]) << 16);
      unsigned int u2 = (unsigned)f2bf(xp[4]) | ((unsigned)f2bf(xp[5]) << 16);
      unsigned int u3 = (unsigned)f2bf(xp[6]) | ((unsigned)f2bf(xp[7]) << 16);
      unsigned int u4 = (unsigned)f2bf(xp[8]);
      unsigned short* op = xbf + (size_t)r * 12;
      *(uint2*)op = make_uint2(u0, u1);
      *(uint2*)(op + 4) = make_uint2(u2, u3);
      *(uint2*)(op + 8) = make_uint2(u4, 0u);
    }
  } else {
    mlp_body(bid - 9 - nScat - nXc, smem, win, W1s, W2T, W3T, w48b);
  }
}

// ===========================================================================
// Node kernel v13 (unchanged from R14): wave-per-node, fused Me, branch-free
// message MFMA + 4-FMA factor epilogue.
// ===========================================================================
__global__ __launch_bounds__(256) void node_kernel(
    const unsigned short* __restrict__ xbf, const float* __restrict__ filt,
    const int* __restrict__ cnt, const int2* __restrict__ slots2,
    const unsigned short* __restrict__ w48b, const float* __restrict__ CT,
    float* __restrict__ out, int N) {
  __shared__ __align__(16) unsigned short meL[4][2304];  // il*144 + d*16 + p
  const int t = threadIdx.x, w = t >> 6, l = t & 63;
  const int n16 = l & 15, g = l >> 4;
  const int Ld = (n16 == 0) ? 0 : ((n16 < 4) ? 1 : 2);
  const bool dok = n16 < 9;
  const int drow = dok ? n16 : 0;
  const bool isg0 = (g == 0), isg1 = (g == 1);
  const int n = blockIdx.x * 4 + w;
  if (n >= N) return;

  int dT0, pT0, dT1, pT1, dT2, pT2, dT3, pT3, dT4, pT4, dT5, pT5;
  bool ok0, ok1, ok2, ok3, ok4, ok5;
  bf16x8 Bme0, Bme1, Bme2, Bme3, Bme4, Bme5;
#define MKB(tt, Bv, dv, pv, okv)                                             \
  {                                                                          \
    const int col = tt * 16 + n16;                                           \
    okv = (col < 81);                                                        \
    dv = okv ? col / 9 : 0;                                                  \
    pv = okv ? col % 9 : 0;                                                  \
    bf16x8 bv;                                                               \
    _Pragma("unroll")                                                        \
    for (int j = 0; j < 8; ++j) bv[j] = (__bf16)0.f;                         \
    if (okv) {                                                               \
      const float* cp = CT + col * 12;                                       \
      if (g == 0) {                                                          \
        const float4 ca = *(const float4*)cp;                                \
        const float4 cb = *(const float4*)(cp + 4);                          \
        bv[0] = (__bf16)ca.x; bv[1] = (__bf16)ca.y;                          \
        bv[2] = (__bf16)ca.z; bv[3] = (__bf16)ca.w;                          \
        bv[4] = (__bf16)cb.x; bv[5] = (__bf16)cb.y;                          \
        bv[6] = (__bf16)cb.z; bv[7] = (__bf16)cb.w;                          \
      } else if (g == 1) {                                                   \
        bv[0] = (__bf16)cp[8];                                               \
      }                                                                      \
    }                                                                        \
    Bv = bv;                                                                 \
  }
  MKB(0, Bme0, dT0, pT0, ok0); MKB(1, Bme1, dT1, pT1, ok1);
  MKB(2, Bme2, dT2, pT2, ok2); MKB(3, Bme3, dT3, pT3, ok3);
  MKB(4, Bme4, dT4, pT4, ok4); MKB(5, Bme5, dT5, pT5, ok5);
#undef MKB

  int deg = cnt[n];
  if (deg > 96) deg = 96;
  const int2* sl2 = slots2 + (size_t)n * 96;
  unsigned short* mlw = &meL[w][0];

  f32x4 accm = {0.f, 0.f, 0.f, 0.f};

  const int nb = (deg + 15) >> 4;
  for (int b = 0; b < nb; ++b) {
    const int base = b * 16;
    const int degb = (deg - base < 16) ? (deg - base) : 16;

    int esx = 0, esy = 0;
    if (n16 < degb) {
      const int2 v = sl2[base + n16];
      esx = v.x; esy = v.y;
    }
    bf16x8 Af;
#pragma unroll
    for (int j = 0; j < 8; ++j) Af[j] = (__bf16)0.f;
    if (n16 < degb) {
      const float* fp = filt + (size_t)esx * 9;
      if (g == 0) {
        const float4 fa = *(const float4*)fp;
        const float4 fb = *(const float4*)(fp + 4);
        Af[0] = (__bf16)fa.x; Af[1] = (__bf16)fa.y;
        Af[2] = (__bf16)fa.z; Af[3] = (__bf16)fa.w;
        Af[4] = (__bf16)fb.x; Af[5] = (__bf16)fb.y;
        Af[6] = (__bf16)fb.z; Af[7] = (__bf16)fb.w;
      } else if (g == 1) {
        Af[0] = (__bf16)fp[8];
      }
    }

#define MEMFMA(Bv, dv, pv, okv)                                              \
    {                                                                        \
      f32x4 a6 = {0.f, 0.f, 0.f, 0.f};                                       \
      a6 = __builtin_amdgcn_mfma_f32_16x16x32_bf16(Af, Bv, a6, 0, 0, 0);     \
      if (okv) {                                                             \
        _Pragma("unroll")                                                    \
        for (int r = 0; r < 4; ++r)                                          \
          mlw[(g * 4 + r) * 144 + dv * 16 + pv] = f2bf(a6[r]);               \
      }                                                                      \
    }
    MEMFMA(Bme0, dT0, pT0, ok0); MEMFMA(Bme1, dT1, pT1, ok1);
    MEMFMA(Bme2, dT2, pT2, ok2); MEMFMA(Bme3, dT3, pT3, ok3);
    MEMFMA(Bme4, dT4, pT4, ok4); MEMFMA(Bme5, dT5, pT5, ok5);
#undef MEMFMA
    __builtin_amdgcn_wave_barrier();

    for (int il = 0; il < degb; ++il) {
      const int e = __builtin_amdgcn_readlane(esx, il);
      const int s = __builtin_amdgcn_readlane(esy, il);

      const unsigned short* xrp = xbf + (size_t)s * 192 + n16 * 12;
      const u32x4 q = *(const u32x4*)xrp;
      const unsigned int qc = *(const unsigned int*)(xrp + 8);

      const uint2 wv =
          *(const uint2*)(w48b + (size_t)e * 64 + Ld * 16 + g * 4);

      const unsigned short* mr = mlw + il * 144 + drow * 16;
      const u32x4 mdv = *(const u32x4*)mr;
      const unsigned int md4 = (*(const unsigned int*)(mr + 8)) & 0xffffu;

      u32x4 av;
      av[0] = isg0 ? q[0] : (isg1 ? qc : 0u);
      av[1] = isg0 ? q[1] : 0u;
      av[2] = isg0 ? q[2] : 0u;
      av[3] = isg0 ? q[3] : 0u;
      u32x4 bv;
      bv[0] = isg0 ? mdv[0] : (isg1 ? md4 : 0u);
      bv[1] = isg0 ? mdv[1] : 0u;
      bv[2] = isg0 ? mdv[2] : 0u;
      bv[3] = isg0 ? mdv[3] : 0u;

      f32x4 c1 = {0.f, 0.f, 0.f, 0.f};
      c1 = __builtin_amdgcn_mfma_f32_16x16x32_bf16(
          __builtin_bit_cast(bf16x8, av), __builtin_bit_cast(bf16x8, bv),
          c1, 0, 0, 0);
      accm[0] = fmaf(c1[0], bfLO(wv.x), accm[0]);
      accm[1] = fmaf(c1[1], bfHI(wv.x), accm[1]);
      accm[2] = fmaf(c1[2], bfLO(wv.y), accm[2]);
      accm[3] = fmaf(c1[3], bfHI(wv.y), accm[3]);
    }
    __builtin_amdgcn_wave_barrier();
  }

  if (dok) {
    float* op = out + (size_t)n * 144 + (g * 4) * 9 + n16;
    op[0]  = accm[0];
    op[9]  = accm[1];
    op[18] = accm[2];
    op[27] = accm[3];
  }
}

// ---------------------------------------------------------------------------
extern "C" void kernel_launch(void* const* d_in, const int* in_sizes, int n_in,
                              void* d_out, int out_size, void* d_ws, size_t ws_size,
                              hipStream_t stream) {
  const float* x      = (const float*)d_in[0];
  const float* filt   = (const float*)d_in[1];
  const float* win    = (const float*)d_in[2];
  const int*   eidx   = (const int*)d_in[3];
  const float* Ux_re  = (const float*)d_in[4];
  const float* Ux_im  = (const float*)d_in[5];
  const float* Uf_re  = (const float*)d_in[6];
  const float* Uf_im  = (const float*)d_in[7];
  const float* Vo_re  = (const float*)d_in[8];
  const float* Vo_im  = (const float*)d_in[9];
  const float* W1     = (const float*)d_in[10];
  const float* W2     = (const float*)d_in[11];
  const float* W3     = (const float*)d_in[12];
  const float* a_w    = (const float*)d_in[13];
  const float* den    = (const float*)d_in[14];
  float* out = (float*)d_out;

  const int N = in_sizes[0] / 144;          // 10000
  const int E = in_sizes[3] / 2;            // 160000
  const int NR = N * 16;                    // x rows (node, m)
  const int* dst = eidx;
  const int* src = eidx + E;

  char* wsb = (char*)d_ws;
  const size_t off_cnt  = 8192;
  const size_t off_slot = off_cnt + 40960;
  const size_t off_w48  = off_slot + (size_t)N * 96 * 8;
  const size_t off_xbf  = off_w48 + (size_t)E * 64 * 2;
  const size_t off_w1s  = off_xbf + (size_t)NR * 12 * 2;
  const size_t off_w2t  = off_w1s + 512 * 4;
  const size_t off_w3t  = off_w2t + 4096 * 2;

  float*          CT    = (float*)wsb;
  int*            cnt   = (int*)(wsb + off_cnt);
  int2*           slot2 = (int2*)(wsb + off_slot);
  unsigned short* w48b  = (unsigned short*)(wsb + off_w48);  // E*64 shorts
  unsigned short* xbf   = (unsigned short*)(wsb + off_xbf);  // NR*12 shorts
  float*          W1s   = (float*)(wsb + off_w1s);
  unsigned short* W2T   = (unsigned short*)(wsb + off_w2t);
  unsigned short* W3T   = (unsigned short*)(wsb + off_w3t);

  const int nMlp  = E / 128;                // 1250
  const int nScat = (E + 255) / 256;        // 625
  const int nXc   = (NR + 255) / 256;       // 625

  hipMemsetAsync(cnt, 0, (size_t)N * sizeof(int), stream);
  wconv_kernel<<<30, 256, 0, stream>>>(W1, W2, W3, a_w, den, W1s, W2T, W3T);
  prep_kernel<<<9 + nScat + nXc + nMlp, 256, 0, stream>>>(
      win, W1s, W2T, W3T, w48b,
      dst, src, E, cnt, slot2,
      x, NR, xbf,
      Ux_re, Ux_im, Uf_re, Uf_im, Vo_re, Vo_im, CT, nScat, nXc);
  node_kernel<<<(N + 3) / 4, 256, 0, stream>>>(
      xbf, filt, cnt, slot2, w48b, CT, out, N);
}